// Round 19
// baseline (658.899 us; speedup 1.0000x reference)
//
#include <hip/hip_runtime.h>
#include <stdint.h>
#include <math.h>

// ---------------------------------------------------------------------------
// SimpleMamba2Like on MI355X — Round 19 (hedged consolidation):
// If ws_size >= 164.5 MiB (5th slot F fits): fuse G1a+G1b into ONE
// gemm256<6> (xp -> A, zp -> F, F survives until G5's gate), dropping the
// second cvt_bf16 + wio_b transpose + one GEMM launch. Otherwise: exact
// round-18 sequence. Device kernels identical to round 18 throughout.
// ---------------------------------------------------------------------------

typedef unsigned short u16;
typedef __bf16 bf16x8 __attribute__((ext_vector_type(8)));
typedef u16 u16x8 __attribute__((ext_vector_type(8)));
typedef u16 u16x4 __attribute__((ext_vector_type(4)));
typedef float f32x4 __attribute__((ext_vector_type(4)));

static constexpr int BB = 4, SS = 2048, DI = 2048, DST = 16, DTR = 128;
static constexpr int MROWS = BB * SS; // 8192
static constexpr int NCH = 16, CL = 128;

__device__ __forceinline__ float bf2f(u16 x) {
  union { unsigned u; float f; } v; v.u = ((unsigned)x) << 16; return v.f;
}
__device__ __forceinline__ u16 f2bf(float f) {
  union { float f; unsigned u; } v; v.f = f;
  unsigned r = (v.u + 0x7FFFu + ((v.u >> 16) & 1u)) >> 16; // RNE
  return (u16)r;
}
__device__ __forceinline__ float sigmoidf_(float x) { return 1.f / (1.f + __expf(-x)); }
__device__ __forceinline__ float softplusf_(float x) {
  return fmaxf(x, 0.f) + log1pf(__expf(-fabsf(x)));
}
__device__ __forceinline__ void async16(u16* lds, const u16* g) {
  __builtin_amdgcn_global_load_lds(
      (__attribute__((address_space(1))) void*)g,
      (__attribute__((address_space(3))) void*)lds, 16, 0, 0);
}

// ---------------------------------------------------------------------------
__global__ __launch_bounds__(256) void cvt_bf16(const float* __restrict__ in,
                                                u16* __restrict__ out, int n4) {
  const int i = blockIdx.x * 256 + threadIdx.x;
  if (i >= n4) return;
  f32x4 v = *(const f32x4*)(in + (size_t)i * 4);
  u16x4 o = { f2bf(v[0]), f2bf(v[1]), f2bf(v[2]), f2bf(v[3]) };
  *(u16x4*)(out + (size_t)i * 4) = o;
}

// ---------------------------------------------------------------------------
// Combine G3 split-K partials. cols<128 -> bf16 dt; cols 128..159 -> ALSO
// raw f32 packed at dbl row-tail bytes [320,448).
// ---------------------------------------------------------------------------
__global__ __launch_bounds__(256) void combine_dbl(const float* __restrict__ P,
                                                   u16* __restrict__ dbl, int n4) {
  const int i = blockIdx.x * 256 + threadIdx.x;
  if (i >= n4) return;
  const float* P1 = P + (size_t)MROWS * 256;
  f32x4 a = *(const f32x4*)(P + (size_t)i * 4);
  f32x4 b = *(const f32x4*)(P1 + (size_t)i * 4);
  f32x4 s = { a[0] + b[0], a[1] + b[1], a[2] + b[2], a[3] + b[3] };
  const int col = (i * 4) & 255;
  const int row = (i * 4) >> 8;
  if (col < 128) {
    u16x4 o = { f2bf(s[0]), f2bf(s[1]), f2bf(s[2]), f2bf(s[3]) };
    *(u16x4*)&dbl[(size_t)row * 256 + col] = o;
  } else if (col < 160) {
    float* fp = (float*)dbl + (size_t)row * 128 + 80 + (col - 128);
    *(f32x4*)fp = s;
  }
}

// ---------------------------------------------------------------------------
// Batched transpose. blockIdx.z selects a descriptor.
// ---------------------------------------------------------------------------
struct TDesc {
  const float* in;
  u16* out;
  int K, N_full, n_off, N_sub, Npad;
};
struct TBatch { TDesc d[5]; int n; };

__global__ void transpose_batch(TBatch batch) {
  if ((int)blockIdx.z >= batch.n) return;
  const TDesc dd = batch.d[blockIdx.z];
  const int k0 = blockIdx.x * 32, n0 = blockIdx.y * 32;
  if (k0 >= dd.K || n0 >= dd.Npad) return; // block-uniform exit (pre-LDS)
  __shared__ u16 tile[32][33];
  const int tx = threadIdx.x, ty = threadIdx.y; // 32 x 8
#pragma unroll
  for (int i = 0; i < 4; ++i) {
    int k = k0 + ty + i * 8, nn = n0 + tx;
    tile[ty + i * 8][tx] =
        (k < dd.K && nn < dd.N_sub)
            ? f2bf(dd.in[(size_t)k * dd.N_full + dd.n_off + nn]) : (u16)0;
  }
  __syncthreads();
#pragma unroll
  for (int i = 0; i < 4; ++i) {
    int nn = n0 + ty + i * 8, k = k0 + tx;
    if (nn < dd.Npad && k < dd.K) dd.out[(size_t)nn * dd.K + k] = tile[tx][ty + i * 8];
  }
}

// ---------------------------------------------------------------------------
// 256x256-tile GEMM (r14): T2-swizzled LDS, wave layout 2M x 4N, one counted
// vmcnt(2) per K-tile (q3), one barrier per phase.
// MODE 1: +bias bf16  MODE 4: *sigmoid(gate) bf16  MODE 6: split store
// ---------------------------------------------------------------------------
template <int MODE>
__global__ __launch_bounds__(512, 1) void gemm256(
    const u16* __restrict__ A, int lda, const u16* __restrict__ BT,
    void* __restrict__ C0v, void* __restrict__ C1v, int ldc, int K,
    const float* __restrict__ bias, const u16* __restrict__ gate, int ldg) {
  __shared__ u16 lds[73728]; // 144 KiB
  const int m0 = blockIdx.x * 256, n0 = blockIdx.y * 256;
  const int t = threadIdx.x, w = t >> 6, l = t & 63;
  const int lr = l & 15, lg = l >> 4;
  const int mhalf = w >> 2, nquad = w & 3;
  const int bslot_h = nquad >> 1, brow0 = (nquad & 1) * 64;
  const int NT = K >> 6;
  const int srow = t >> 3;
  const int sc8 = (t & 7) ^ (srow & 7); // T2: inverse-swizzled source col
  const int rsw = (lr & 7) << 3;        // T2: element-XOR for ds_read

#define A1SLOT(tile) ((((tile) & 1)) * 8192)
#define A0SLOT(s3) (16384 + (s3) * 8192)
#define BSLOT(tile, h) (40960 + (((tile) & 1) * 2 + (h)) * 8192)
#define STAGE_A0(tile, s3)                                                      \
  {                                                                             \
    const u16* _g = A + (size_t)(m0 + srow) * lda + (tile) * 64 + sc8 * 8;      \
    async16(&lds[A0SLOT(s3) + w * 512], _g);                                    \
    async16(&lds[A0SLOT(s3) + 4096 + w * 512], _g + (size_t)64 * lda);          \
  }
#define STAGE_A1(tile)                                                          \
  {                                                                             \
    const u16* _g = A + (size_t)(m0 + 128 + srow) * lda + (tile) * 64 + sc8 * 8;\
    async16(&lds[A1SLOT(tile) + w * 512], _g);                                  \
    async16(&lds[A1SLOT(tile) + 4096 + w * 512], _g + (size_t)64 * lda);        \
  }
#define STAGE_B(tile, h)                                                        \
  {                                                                             \
    const u16* _g = BT + (size_t)(n0 + (h) * 128 + srow) * K +                  \
                    (tile) * 64 + sc8 * 8;                                      \
    async16(&lds[BSLOT(tile, h) + w * 512], _g);                                \
    async16(&lds[BSLOT(tile, h) + 4096 + w * 512], _g + (size_t)64 * K);        \
  }

  f32x4 acc[8][4] = {};
  u16x8 bfr[4][2];

  STAGE_A0(0, 0); STAGE_A1(0); STAGE_B(0, 0); STAGE_B(0, 1); STAGE_A0(1, 1);
  asm volatile("s_waitcnt vmcnt(2)" ::: "memory");
  __builtin_amdgcn_s_barrier();
  asm volatile("" ::: "memory");
  int cur0 = 0;

  for (int T = 0; T < NT; ++T) {
    const int abase = mhalf ? A1SLOT(T) : A0SLOT(cur0);
    const int bbase = BSLOT(T, bslot_h);
#pragma unroll
    for (int q = 0; q < 4; ++q) {
      if (q == 0) {
#pragma unroll
        for (int fn = 0; fn < 4; ++fn)
#pragma unroll
          for (int ks = 0; ks < 2; ++ks)
            bfr[fn][ks] = *(const u16x8*)&lds[
                bbase + (brow0 + fn * 16 + lr) * 64 + ((ks * 32 + lg * 8) ^ rsw)];
      }
      u16x8 af[2][2];
#pragma unroll
      for (int j = 0; j < 2; ++j)
#pragma unroll
        for (int ks = 0; ks < 2; ++ks)
          af[j][ks] = *(const u16x8*)&lds[
              abase + ((q * 2 + j) * 16 + lr) * 64 + ((ks * 32 + lg * 8) ^ rsw)];
      if (q == 0) { if (T + 1 < NT) { STAGE_B(T + 1, 0); STAGE_A1(T + 1); } }
      else if (q == 1) { if (T + 1 < NT) { STAGE_B(T + 1, 1); } }
      else if (q == 2) {
        if (T + 2 < NT) {
          int s3 = cur0 + 2; if (s3 >= 3) s3 -= 3;
          STAGE_A0(T + 2, s3);
        }
      }
      if (q == 3) asm volatile("s_waitcnt vmcnt(2)" ::: "memory");
      __builtin_amdgcn_s_barrier();
      asm volatile("" ::: "memory");
      __builtin_amdgcn_s_setprio(1);
#pragma unroll
      for (int j = 0; j < 2; ++j)
#pragma unroll
        for (int fn = 0; fn < 4; ++fn)
#pragma unroll
          for (int ks = 0; ks < 2; ++ks)
            acc[q * 2 + j][fn] = __builtin_amdgcn_mfma_f32_16x16x32_bf16(
                __builtin_bit_cast(bf16x8, af[j][ks]),
                __builtin_bit_cast(bf16x8, bfr[fn][ks]), acc[q * 2 + j][fn],
                0, 0, 0);
      __builtin_amdgcn_s_setprio(0);
    }
    ++cur0; if (cur0 == 3) cur0 = 0;
  }

#pragma unroll
  for (int fm = 0; fm < 8; ++fm) {
#pragma unroll
    for (int fn = 0; fn < 4; ++fn) {
#pragma unroll
      for (int r = 0; r < 4; ++r) {
        const int row = m0 + mhalf * 128 + fm * 16 + lg * 4 + r;
        const int col = n0 + nquad * 64 + fn * 16 + lr;
        float v = acc[fm][fn][r];
        if constexpr (MODE == 1) v += bias[col];
        if constexpr (MODE == 4) v *= sigmoidf_(bf2f(gate[(size_t)row * ldg + col]));
        if constexpr (MODE == 6) {
          if (col < 2048) ((u16*)C0v)[(size_t)row * ldc + col] = f2bf(v);
          else            ((u16*)C1v)[(size_t)row * ldc + col - 2048] = f2bf(v);
        } else {
          ((u16*)C0v)[(size_t)row * ldc + col] = f2bf(v);
        }
      }
    }
  }
#undef A1SLOT
#undef A0SLOT
#undef BSLOT
#undef STAGE_A0
#undef STAGE_A1
#undef STAGE_B
}

// ---------------------------------------------------------------------------
// 128x128 GEMM. ldb = BT row stride. MODE 0: bf16; 3: +bias, softplus;
// 5: +bias, f32 store; 7: f32 partial store (split-K via blockIdx.z).
// ---------------------------------------------------------------------------
template <int MODE>
__global__ __launch_bounds__(256) void gemm_bt(
    const u16* __restrict__ A, int lda, const u16* __restrict__ BT, int ldb,
    void* __restrict__ Cv, int ldc, int K,
    const float* __restrict__ bias, const u16* __restrict__ gate, int ldg) {
  __shared__ u16 Asm[128 * 32];
  __shared__ u16 Bsm[128 * 32];
  const int m0 = blockIdx.x * 128, n0 = blockIdx.y * 128;
  if constexpr (MODE == 7) {
    const int kz = blockIdx.z;
    A += (size_t)kz * 1024;
    BT += (size_t)kz * 1024;
  }
  const int t = threadIdx.x;
  const int wave = t >> 6, lane = t & 63;
  const int wm = (wave >> 1) * 64, wn = (wave & 1) * 64;
  const int lr = lane & 15, lg = lane >> 4;
  const int sr = t >> 2, sc = (t & 3) * 8;
  const int wbase = wave * 512;
  const u16* Ap0 = A + (size_t)(m0 + sr) * lda + sc;
  const u16* Ap1 = A + (size_t)(m0 + 64 + sr) * lda + sc;
  const u16* Bp0 = BT + (size_t)(n0 + sr) * ldb + sc;
  const u16* Bp1 = BT + (size_t)(n0 + 64 + sr) * ldb + sc;

  f32x4 acc[4][4] = {};
  const int nk = K >> 5;
  for (int kt = 0; kt < nk; ++kt) {
    const int ko = kt * 32;
    __syncthreads();
    async16(&Asm[wbase], Ap0 + ko);
    async16(&Asm[2048 + wbase], Ap1 + ko);
    async16(&Bsm[wbase], Bp0 + ko);
    async16(&Bsm[2048 + wbase], Bp1 + ko);
    __syncthreads();
    u16x8 afu[4], bfu[4];
#pragma unroll
    for (int i = 0; i < 4; ++i)
      afu[i] = *(const u16x8*)&Asm[(wm + i * 16 + lr) * 32 + lg * 8];
#pragma unroll
    for (int j = 0; j < 4; ++j)
      bfu[j] = *(const u16x8*)&Bsm[(wn + j * 16 + lr) * 32 + lg * 8];
#pragma unroll
    for (int i = 0; i < 4; ++i)
#pragma unroll
      for (int j = 0; j < 4; ++j)
        acc[i][j] = __builtin_amdgcn_mfma_f32_16x16x32_bf16(
            __builtin_bit_cast(bf16x8, afu[i]), __builtin_bit_cast(bf16x8, bfu[j]),
            acc[i][j], 0, 0, 0);
  }
#pragma unroll
  for (int i = 0; i < 4; ++i) {
#pragma unroll
    for (int j = 0; j < 4; ++j) {
#pragma unroll
      for (int r = 0; r < 4; ++r) {
        const int row = m0 + wm + i * 16 + lg * 4 + r;
        const int col = n0 + wn + j * 16 + lr;
        float v = acc[i][j][r];
        if constexpr (MODE == 3 || MODE == 5) v += bias[col];
        if constexpr (MODE == 3) v = softplusf_(v);
        if constexpr (MODE == 5)
          ((float*)Cv)[(size_t)row * ldc + col] = v;
        else if constexpr (MODE == 7)
          ((float*)Cv)[(size_t)blockIdx.z * MROWS * 256 + (size_t)row * ldc + col] = v;
        else
          ((u16*)Cv)[(size_t)row * ldc + col] = f2bf(v);
      }
    }
  }
}

// ---------------------------------------------------------------------------
// Causal depthwise conv (k=4) + SiLU, vectorized: 1 thread = 8 d's.
// ---------------------------------------------------------------------------
__global__ __launch_bounds__(256) void conv_silu(
    const u16* __restrict__ xm, const float* __restrict__ cw,
    const float* __restrict__ cb, u16* __restrict__ xc) {
  const int tid = blockIdx.x * 256 + threadIdx.x; // over MROWS*DI/8
  const size_t base = (size_t)tid * 8;
  const int d8 = (int)(base & (DI - 1));
  const int row = (int)(base >> 11);
  const int s = row & (SS - 1);
  u16x8 xv[4];
#pragma unroll
  for (int j = 0; j < 4; ++j) {
    xv[j] = ((s - 3 + j) >= 0) ? *(const u16x8*)&xm[(size_t)(row - 3 + j) * DI + d8]
                               : (u16x8){0, 0, 0, 0, 0, 0, 0, 0};
  }
  u16x8 o;
#pragma unroll
  for (int dd = 0; dd < 8; ++dd) {
    f32x4 wv = *(const f32x4*)(cw + (size_t)(d8 + dd) * 4);
    float acc = cb[d8 + dd];
#pragma unroll
    for (int j = 0; j < 4; ++j)
      acc += bf2f(xv[j][dd]) * wv[j];
    float r = acc * sigmoidf_(acc);
    o[dd] = f2bf(r);
  }
  *(u16x8*)&xc[base] = o;
}

// ---------------------------------------------------------------------------
// Serial-n chunk-parallel scan; B/C read as raw f32 from dbl row tail.
// ---------------------------------------------------------------------------
__global__ __launch_bounds__(256) void scan_phaseA(
    const u16* __restrict__ delta, const u16* __restrict__ dbl,
    const u16* __restrict__ u_in,
    float* __restrict__ Pb, float* __restrict__ Sb) {
  const int t = threadIdx.x;
  const int bid = blockIdx.x;
  const int dblk = bid & 7;
  const int c = (bid >> 3) & 15;
  const int b = bid >> 7;
  const int d = dblk * 256 + t;
  const int s0 = c * CL;
  const u16* dp = delta + (size_t)(b * SS + s0) * DI + d;
  const u16* up = u_in + (size_t)(b * SS + s0) * DI + d;
  const float* bcf = (const float*)dbl + (size_t)(b * SS + s0) * 128 + 80;
  float h[16];
#pragma unroll
  for (int n = 0; n < 16; ++n) h[n] = 0.f;
  float L = 0.f;
  float dt_c = bf2f(dp[0]);
  float u_c = bf2f(up[0]);
  for (int s = 0; s < CL; ++s) {
    dp += DI; up += DI;
    float dt_n = bf2f(dp[0]); // 1-step prefetch
    float u_n = bf2f(up[0]);
    f32x4 wB[4];
#pragma unroll
    for (int i = 0; i < 4; ++i) wB[i] = *(const f32x4*)(bcf + 4 * i);
    bcf += 128;
    float e1 = __expf(-dt_c);
    float dtu = dt_c * u_c;
    L += dt_c;
    float e = 1.f;
#pragma unroll
    for (int i = 0; i < 4; ++i) {
#pragma unroll
      for (int k = 0; k < 4; ++k) {
        e *= e1;
        h[4 * i + k] = fmaf(e, h[4 * i + k], dtu * wB[i][k]);
      }
    }
    dt_c = dt_n; u_c = u_n;
  }
  const float E = __expf(-L);
  const size_t base = (((size_t)(b * DI + d)) * 16) * NCH + c;
  float P = 1.f;
#pragma unroll
  for (int n = 0; n < 16; ++n) {
    P *= E;
    Pb[base + (size_t)n * NCH] = P;
    Sb[base + (size_t)n * NCH] = h[n];
  }
}

__global__ __launch_bounds__(256) void scan_phaseB(
    const float* __restrict__ Pb, const float* __restrict__ Sb,
    float* __restrict__ Hb) {
  const size_t tid = (size_t)blockIdx.x * 256 + threadIdx.x;
  const size_t base = tid * NCH;
  float h = 0.f;
#pragma unroll
  for (int cc = 0; cc < NCH; ++cc) {
    Hb[base + cc] = h;
    h = Sb[base + cc] + Pb[base + cc] * h;
  }
}

__global__ __launch_bounds__(256) void scan_phaseC(
    const u16* __restrict__ delta, const u16* __restrict__ dbl,
    const u16* __restrict__ u_in, u16* __restrict__ zy,
    const float* __restrict__ D_skip, const float* __restrict__ Hb) {
  const int t = threadIdx.x;
  const int bid = blockIdx.x;
  const int dblk = bid & 7;
  const int c = (bid >> 3) & 15;
  const int b = bid >> 7;
  const int d = dblk * 256 + t;
  const float Dsk = D_skip[d];
  const size_t hbase = (((size_t)(b * DI + d)) * 16) * NCH + c;
  float h[16];
#pragma unroll
  for (int n = 0; n < 16; ++n) h[n] = Hb[hbase + (size_t)n * NCH];
  const int s0 = c * CL;
  const u16* dp = delta + (size_t)(b * SS + s0) * DI + d;
  const u16* up = u_in + (size_t)(b * SS + s0) * DI + d;
  u16* zp = zy + (size_t)(b * SS + s0) * DI + d;
  const float* bcf = (const float*)dbl + (size_t)(b * SS + s0) * 128 + 80;
  float dt_c = bf2f(dp[0]);
  float u_c = bf2f(up[0]);
  float z_c = bf2f(zp[0]);
  for (int s = 0; s < CL; ++s) {
    dp += DI; up += DI;
    float dt_n = bf2f(dp[0]); // 1-step prefetch
    float u_n = bf2f(up[0]);
    float z_n = bf2f(zp[DI]);
    f32x4 wB[4], wC[4];
#pragma unroll
    for (int i = 0; i < 4; ++i) {
      wB[i] = *(const f32x4*)(bcf + 4 * i);
      wC[i] = *(const f32x4*)(bcf + 16 + 4 * i);
    }
    bcf += 128;
    float e1 = __expf(-dt_c);
    float dtu = dt_c * u_c;
    float e = 1.f, y = 0.f;
#pragma unroll
    for (int i = 0; i < 4; ++i) {
#pragma unroll
      for (int k = 0; k < 4; ++k) {
        e *= e1;
        h[4 * i + k] = fmaf(e, h[4 * i + k], dtu * wB[i][k]);
        y = fmaf(h[4 * i + k], wC[i][k], y);
      }
    }
    float yo = (y + Dsk * u_c) * (z_c * sigmoidf_(z_c));
    zp[0] = f2bf(yo);
    zp += DI;
    dt_c = dt_n; u_c = u_n; z_c = z_n;
  }
}

// ---------------------------------------------------------------------------
extern "C" void kernel_launch(void* const* d_in, const int* in_sizes, int n_in,
                              void* d_out, int out_size, void* d_ws, size_t ws_size,
                              hipStream_t stream) {
  const float* x       = (const float*)d_in[0];
  const float* W_in_o  = (const float*)d_in[1];
  const float* b_in_o  = (const float*)d_in[2];
  const float* W_out_o = (const float*)d_in[3];
  const float* b_out_o = (const float*)d_in[4];
  const float* W_in_i  = (const float*)d_in[5];
  const float* conv_w  = (const float*)d_in[6];
  const float* conv_b  = (const float*)d_in[7];
  const float* W_xp    = (const float*)d_in[8];
  const float* W_dt    = (const float*)d_in[9];
  const float* b_dt    = (const float*)d_in[10];
  const float* D_skip  = (const float*)d_in[12];
  const float* W_out_i = (const float*)d_in[13];
  float* out = (float*)d_out;
  char* ws = (char*)d_ws;

  const size_t SLOT = (size_t)MROWS * DI * 2; // 32 MiB
  const size_t o_A = 0, o_B = SLOT, o_C = 2 * SLOT, o_E = 3 * SLOT;
  const size_t o_F = 4 * SLOT; // path A only
  const size_t tail4 = 4 * SLOT, tail5 = 5 * SLOT;
  const size_t need4 = tail4 + (size_t)MROWS * 256 * 2 + (size_t)2048 * 128 * 2;
  const size_t need5 = tail5 + (size_t)MROWS * 256 * 2 + (size_t)2048 * 128 * 2;
  if (need4 > ws_size) return;
  const bool five = (need5 <= ws_size);
  const size_t o_dbl = five ? tail5 : tail4;
  const size_t o_wdt = o_dbl + (size_t)MROWS * 256 * 2;

  u16* Abuf = (u16*)(ws + o_A);
  u16* Bbuf = (u16*)(ws + o_B);
  u16* Cbuf = (u16*)(ws + o_C);
  u16* Ebuf = (u16*)(ws + o_E);
  u16* Fbuf = (u16*)(ws + o_F);
  u16* dbl  = (u16*)(ws + o_dbl);
  u16* wdt  = (u16*)(ws + o_wdt);
  float* Pb = (float*)(ws + o_B);
  float* Sb = Pb + (size_t)2097152;
  float* Hb = Sb + (size_t)2097152;
  float* g3part = (float*)(ws + o_B);

  if (five) {
    // ----- Path A: fused G1 (xp->A, zp->F persists to G5) -----
    u16* wio = Ebuf;              // 4096 x 1024 (8 MiB)
    u16* wii = Ebuf + 4194304;    // 4096 x 2048 (16 MiB)
    u16* wxp = Ebuf + 12582912;   // 256 x 2048  (1 MiB)
    u16* woi = Bbuf;              // post-scan reuse of B
    u16* woo = Bbuf + 4194304;

    cvt_bf16<<<(MROWS * 1024 / 4 + 255) / 256, 256, 0, stream>>>(x, Bbuf, MROWS * 1024 / 4);
    {
      TBatch tb1;
      tb1.n = 4;
      tb1.d[0] = { W_in_o, wio, 1024, 4096, 0, 4096, 4096 };
      tb1.d[1] = { W_in_i, wii, 2048, 4096, 0, 2048, 2048 };
      tb1.d[2] = { W_in_i, wii + (size_t)2048 * 2048, 2048, 4096, 2048, 2048, 2048 };
      tb1.d[3] = { W_xp, wxp, 2048, 160, 0, 160, 256 };
      tb1.d[4] = { W_dt, wdt, 128, 2048, 0, 2048, 2048 };
      tb1.n = 5;
      transpose_batch<<<dim3(64, 128, 5), dim3(32, 8), 0, stream>>>(tb1);
    }
    // G1 fused: xp|zp = x_bf @ wio + b_in_o (N=4096, split xp->A zp->F)
    gemm256<6><<<dim3(32, 16), 512, 0, stream>>>(Bbuf, 1024, wio, Abuf, Fbuf, 2048, 1024, nullptr, nullptr, 0);
    // NOTE: MODE 6 has no bias — add bias via gate-free path? b_in_o must be
    // applied. Use a tiny bias-add pass fused into G2/G5 would change math.
    // Instead: apply bias inside G2's A-read is impossible; so add bias here:
    // handled by bias2 kernel below.
    // (bias over xp cols 0..2047 -> Abuf; zp cols 2048..4095 -> Fbuf)
    {
      // bias-add elementwise: A += b[0:2048] per col; F += b[2048:4096]
      // grid over MROWS*2048/4 for each
      // reuse cvt-style kernel? implemented inline below as lambda-kernels
    }
    // Apply biases with two lightweight passes (cols cycle every 2048):
    // declared below as bias_add kernel launches
    extern __global__ void bias_add_dummy(); // (no-op declaration guard)
    // fallthrough continues below
    {
      struct Local {};
    }
    // bias_add launches:
    {
      void* unused = nullptr; (void)unused;
    }
    // Use bias_add kernel:
    {
      // see bias_add definition after kernel_launch (forward-declared above main flow)
    }
    // -- the actual launches:
    {
      extern void launch_bias(u16*, const float*, int, hipStream_t);
    }
    // Simplicity: biases applied by bias_add kernel defined globally below.
    {
    }
    // (real calls)
    {
      extern __global__ void bias_add(u16* buf, const float* bias, int n4);
      bias_add<<<(MROWS * 2048 / 4 + 255) / 256, 256, 0, stream>>>(Abuf, b_in_o, MROWS * 2048 / 4);
      bias_add<<<(MROWS * 2048 / 4 + 255) / 256, 256, 0, stream>>>(Fbuf, b_in_o + 2048, MROWS * 2048 / 4);
    }
    // G2: xm|zm = xp @ wii
    gemm256<6><<<dim3(32, 16), 512, 0, stream>>>(Abuf, 2048, wii, Bbuf, Cbuf, 2048, 2048, nullptr, nullptr, 0);
    conv_silu<<<(MROWS * DI / 8) / 256, 256, 0, stream>>>(Bbuf, conv_w, conv_b, Abuf);
    gemm_bt<7><<<dim3(64, 2, 2), 256, 0, stream>>>(Abuf, 2048, wxp, 2048, g3part, 256, 1024, nullptr, nullptr, 0);
    combine_dbl<<<(MROWS * 256 / 4 + 255) / 256, 256, 0, stream>>>(g3part, dbl, MROWS * 256 / 4);
    gemm_bt<3><<<dim3(64, 16), 256, 0, stream>>>(dbl, 256, wdt, 128, Ebuf, 2048, 128, b_dt, nullptr, 0);
    scan_phaseA<<<BB * NCH * 8, 256, 0, stream>>>(Ebuf, dbl, Abuf, Pb, Sb);
    scan_phaseB<<<512, 256, 0, stream>>>(Pb, Sb, Hb);
    scan_phaseC<<<BB * NCH * 8, 256, 0, stream>>>(Ebuf, dbl, Abuf, Cbuf, D_skip, Hb);
    {
      TBatch tb2;
      tb2.n = 2;
      tb2.d[0] = { W_out_i, woi, 2048, 2048, 0, 2048, 2048 };
      tb2.d[1] = { W_out_o, woo, 2048, 1024, 0, 1024, 1024 };
      tb2.d[2] = { nullptr, nullptr, 0, 0, 0, 0, 0 };
      tb2.d[3] = { nullptr, nullptr, 0, 0, 0, 0, 0 };
      tb2.d[4] = { nullptr, nullptr, 0, 0, 0, 0, 0 };
      transpose_batch<<<dim3(64, 64, 2), dim3(32, 8), 0, stream>>>(tb2);
    }
    gemm256<4><<<dim3(32, 8), 512, 0, stream>>>(Cbuf, 2048, woi, Abuf, nullptr, 2048, 2048, nullptr, Fbuf, 2048);
    gemm_bt<5><<<dim3(64, 8), 256, 0, stream>>>(Abuf, 2048, woo, 2048, out, 1024, 2048, b_out_o, nullptr, 0);
  } else {
    // ----- Path B: exact round-18 sequence -----
    u16* wio_a = Ebuf;
    u16* wii   = Ebuf + 2097152;
    u16* wxp   = Ebuf + 10485760;
    u16* wio_b = Bbuf;
    u16* woi   = Bbuf + 2097152;
    u16* woo   = Bbuf + 6291456;
    u16* xbf2  = Bbuf + 8388608;

    cvt_bf16<<<(MROWS * 1024 / 4 + 255) / 256, 256, 0, stream>>>(x, Bbuf, MROWS * 1024 / 4);
    {
      TBatch tb1;
      tb1.n = 5;
      tb1.d[0] = { W_in_o, wio_a, 1024, 4096, 0, 2048, 2048 };
      tb1.d[1] = { W_in_i, wii, 2048, 4096, 0, 2048, 2048 };
      tb1.d[2] = { W_in_i, wii + (size_t)2048 * 2048, 2048, 4096, 2048, 2048, 2048 };
      tb1.d[3] = { W_xp, wxp, 2048, 160, 0, 160, 256 };
      tb1.d[4] = { W_dt, wdt, 128, 2048, 0, 2048, 2048 };
      transpose_batch<<<dim3(64, 64, 5), dim3(32, 8), 0, stream>>>(tb1);
    }
    gemm256<1><<<dim3(32, 8), 512, 0, stream>>>(Bbuf, 1024, wio_a, Abuf, nullptr, 2048, 1024, b_in_o, nullptr, 0);
    gemm256<6><<<dim3(32, 16), 512, 0, stream>>>(Abuf, 2048, wii, Bbuf, Cbuf, 2048, 2048, nullptr, nullptr, 0);
    conv_silu<<<(MROWS * DI / 8) / 256, 256, 0, stream>>>(Bbuf, conv_w, conv_b, Abuf);
    gemm_bt<7><<<dim3(64, 2, 2), 256, 0, stream>>>(Abuf, 2048, wxp, 2048, g3part, 256, 1024, nullptr, nullptr, 0);
    combine_dbl<<<(MROWS * 256 / 4 + 255) / 256, 256, 0, stream>>>(g3part, dbl, MROWS * 256 / 4);
    gemm_bt<3><<<dim3(64, 16), 256, 0, stream>>>(dbl, 256, wdt, 128, Ebuf, 2048, 128, b_dt, nullptr, 0);
    scan_phaseA<<<BB * NCH * 8, 256, 0, stream>>>(Ebuf, dbl, Abuf, Pb, Sb);
    scan_phaseB<<<512, 256, 0, stream>>>(Pb, Sb, Hb);
    scan_phaseC<<<BB * NCH * 8, 256, 0, stream>>>(Ebuf, dbl, Abuf, Cbuf, D_skip, Hb);
    cvt_bf16<<<(MROWS * 1024 / 4 + 255) / 256, 256, 0, stream>>>(x, xbf2, MROWS * 1024 / 4);
    {
      TBatch tb2;
      tb2.n = 3;
      tb2.d[0] = { W_in_o, wio_b, 1024, 4096, 2048, 2048, 2048 };
      tb2.d[1] = { W_out_i, woi, 2048, 2048, 0, 2048, 2048 };
      tb2.d[2] = { W_out_o, woo, 2048, 1024, 0, 1024, 1024 };
      tb2.d[3] = { nullptr, nullptr, 0, 0, 0, 0, 0 };
      tb2.d[4] = { nullptr, nullptr, 0, 0, 0, 0, 0 };
      transpose_batch<<<dim3(64, 64, 3), dim3(32, 8), 0, stream>>>(tb2);
    }
    gemm256<1><<<dim3(32, 8), 512, 0, stream>>>(xbf2, 1024, wio_b, Ebuf, nullptr, 2048, 1024, b_in_o + 2048, nullptr, 0);
    gemm256<4><<<dim3(32, 8), 512, 0, stream>>>(Cbuf, 2048, woi, Abuf, nullptr, 2048, 2048, nullptr, Ebuf, 2048);
    gemm_bt<5><<<dim3(64, 8), 256, 0, stream>>>(Abuf, 2048, woo, 2048, out, 1024, 2048, b_out_o, nullptr, 0);
  }
}

// ---------------------------------------------------------------------------
// bias_add: buf[i] = bf16(bf2f(buf[i]) + bias[col]), cols cycle mod 2048.
// (Used by path A to apply b_in_o after the bias-less fused G1.)
// ---------------------------------------------------------------------------
__global__ __launch_bounds__(256) void bias_add(u16* __restrict__ buf,
                                                const float* __restrict__ bias,
                                                int n4) {
  const int i = blockIdx.x * 256 + threadIdx.x;
  if (i >= n4) return;
  const int col = (i * 4) & 2047;
  u16x4 v = *(u16x4*)&buf[(size_t)i * 4];
  u16x4 o = { f2bf(bf2f(v[0]) + bias[col]),
              f2bf(bf2f(v[1]) + bias[col + 1]),
              f2bf(bf2f(v[2]) + bias[col + 2]),
              f2bf(bf2f(v[3]) + bias[col + 3]) };
  *(u16x4*)&buf[(size_t)i * 4] = o;
}

// Round 20
// 657.130 us; speedup vs baseline: 1.0027x; 1.0027x over previous
//
#include <hip/hip_runtime.h>
#include <stdint.h>
#include <math.h>

// ---------------------------------------------------------------------------
// SimpleMamba2Like on MI355X — Round 20: r19's fused-G1 done right.
// MODE 6 now applies bias[col] (full-width, col in [0,4096)) in the f32
// accumulator (uniform branch) — the two 64-MiB bias_add passes that caused
// r19's regression are deleted. Path A (ws >= 164.5 MiB, known true): fused
// G1 (xp->A, zp->F persists to G5), single cvt_bf16, merged transposes.
// Path B fallback = exact round-18. All other kernels identical to r18.
// ---------------------------------------------------------------------------

typedef unsigned short u16;
typedef __bf16 bf16x8 __attribute__((ext_vector_type(8)));
typedef u16 u16x8 __attribute__((ext_vector_type(8)));
typedef u16 u16x4 __attribute__((ext_vector_type(4)));
typedef float f32x4 __attribute__((ext_vector_type(4)));

static constexpr int BB = 4, SS = 2048, DI = 2048, DST = 16, DTR = 128;
static constexpr int MROWS = BB * SS; // 8192
static constexpr int NCH = 16, CL = 128;

__device__ __forceinline__ float bf2f(u16 x) {
  union { unsigned u; float f; } v; v.u = ((unsigned)x) << 16; return v.f;
}
__device__ __forceinline__ u16 f2bf(float f) {
  union { float f; unsigned u; } v; v.f = f;
  unsigned r = (v.u + 0x7FFFu + ((v.u >> 16) & 1u)) >> 16; // RNE
  return (u16)r;
}
__device__ __forceinline__ float sigmoidf_(float x) { return 1.f / (1.f + __expf(-x)); }
__device__ __forceinline__ float softplusf_(float x) {
  return fmaxf(x, 0.f) + log1pf(__expf(-fabsf(x)));
}
__device__ __forceinline__ void async16(u16* lds, const u16* g) {
  __builtin_amdgcn_global_load_lds(
      (__attribute__((address_space(1))) void*)g,
      (__attribute__((address_space(3))) void*)lds, 16, 0, 0);
}

// ---------------------------------------------------------------------------
__global__ __launch_bounds__(256) void cvt_bf16(const float* __restrict__ in,
                                                u16* __restrict__ out, int n4) {
  const int i = blockIdx.x * 256 + threadIdx.x;
  if (i >= n4) return;
  f32x4 v = *(const f32x4*)(in + (size_t)i * 4);
  u16x4 o = { f2bf(v[0]), f2bf(v[1]), f2bf(v[2]), f2bf(v[3]) };
  *(u16x4*)(out + (size_t)i * 4) = o;
}

// ---------------------------------------------------------------------------
// Combine G3 split-K partials. cols<128 -> bf16 dt; cols 128..159 -> ALSO
// raw f32 packed at dbl row-tail bytes [320,448).
// ---------------------------------------------------------------------------
__global__ __launch_bounds__(256) void combine_dbl(const float* __restrict__ P,
                                                   u16* __restrict__ dbl, int n4) {
  const int i = blockIdx.x * 256 + threadIdx.x;
  if (i >= n4) return;
  const float* P1 = P + (size_t)MROWS * 256;
  f32x4 a = *(const f32x4*)(P + (size_t)i * 4);
  f32x4 b = *(const f32x4*)(P1 + (size_t)i * 4);
  f32x4 s = { a[0] + b[0], a[1] + b[1], a[2] + b[2], a[3] + b[3] };
  const int col = (i * 4) & 255;
  const int row = (i * 4) >> 8;
  if (col < 128) {
    u16x4 o = { f2bf(s[0]), f2bf(s[1]), f2bf(s[2]), f2bf(s[3]) };
    *(u16x4*)&dbl[(size_t)row * 256 + col] = o;
  } else if (col < 160) {
    float* fp = (float*)dbl + (size_t)row * 128 + 80 + (col - 128);
    *(f32x4*)fp = s;
  }
}

// ---------------------------------------------------------------------------
// Batched transpose. blockIdx.z selects a descriptor.
// ---------------------------------------------------------------------------
struct TDesc {
  const float* in;
  u16* out;
  int K, N_full, n_off, N_sub, Npad;
};
struct TBatch { TDesc d[5]; int n; };

__global__ void transpose_batch(TBatch batch) {
  if ((int)blockIdx.z >= batch.n) return;
  const TDesc dd = batch.d[blockIdx.z];
  const int k0 = blockIdx.x * 32, n0 = blockIdx.y * 32;
  if (k0 >= dd.K || n0 >= dd.Npad) return; // block-uniform exit (pre-LDS)
  __shared__ u16 tile[32][33];
  const int tx = threadIdx.x, ty = threadIdx.y; // 32 x 8
#pragma unroll
  for (int i = 0; i < 4; ++i) {
    int k = k0 + ty + i * 8, nn = n0 + tx;
    tile[ty + i * 8][tx] =
        (k < dd.K && nn < dd.N_sub)
            ? f2bf(dd.in[(size_t)k * dd.N_full + dd.n_off + nn]) : (u16)0;
  }
  __syncthreads();
#pragma unroll
  for (int i = 0; i < 4; ++i) {
    int nn = n0 + ty + i * 8, k = k0 + tx;
    if (nn < dd.Npad && k < dd.K) dd.out[(size_t)nn * dd.K + k] = tile[tx][ty + i * 8];
  }
}

// ---------------------------------------------------------------------------
// 256x256-tile GEMM (r14 schedule): T2-swizzled LDS, wave layout 2M x 4N,
// one counted vmcnt(2) per K-tile (q3), one barrier per phase.
// MODE 1: +bias bf16  MODE 4: *sigmoid(gate) bf16
// MODE 6: split store col<2048 -> C0 else C1; if bias != nullptr, adds
//         bias[col] (full 4096-wide vector) in the f32 accumulator.
// ---------------------------------------------------------------------------
template <int MODE>
__global__ __launch_bounds__(512, 1) void gemm256(
    const u16* __restrict__ A, int lda, const u16* __restrict__ BT,
    void* __restrict__ C0v, void* __restrict__ C1v, int ldc, int K,
    const float* __restrict__ bias, const u16* __restrict__ gate, int ldg) {
  __shared__ u16 lds[73728]; // 144 KiB
  const int m0 = blockIdx.x * 256, n0 = blockIdx.y * 256;
  const int t = threadIdx.x, w = t >> 6, l = t & 63;
  const int lr = l & 15, lg = l >> 4;
  const int mhalf = w >> 2, nquad = w & 3;
  const int bslot_h = nquad >> 1, brow0 = (nquad & 1) * 64;
  const int NT = K >> 6;
  const int srow = t >> 3;
  const int sc8 = (t & 7) ^ (srow & 7); // T2: inverse-swizzled source col
  const int rsw = (lr & 7) << 3;        // T2: element-XOR for ds_read

#define A1SLOT(tile) ((((tile) & 1)) * 8192)
#define A0SLOT(s3) (16384 + (s3) * 8192)
#define BSLOT(tile, h) (40960 + (((tile) & 1) * 2 + (h)) * 8192)
#define STAGE_A0(tile, s3)                                                      \
  {                                                                             \
    const u16* _g = A + (size_t)(m0 + srow) * lda + (tile) * 64 + sc8 * 8;      \
    async16(&lds[A0SLOT(s3) + w * 512], _g);                                    \
    async16(&lds[A0SLOT(s3) + 4096 + w * 512], _g + (size_t)64 * lda);          \
  }
#define STAGE_A1(tile)                                                          \
  {                                                                             \
    const u16* _g = A + (size_t)(m0 + 128 + srow) * lda + (tile) * 64 + sc8 * 8;\
    async16(&lds[A1SLOT(tile) + w * 512], _g);                                  \
    async16(&lds[A1SLOT(tile) + 4096 + w * 512], _g + (size_t)64 * lda);        \
  }
#define STAGE_B(tile, h)                                                        \
  {                                                                             \
    const u16* _g = BT + (size_t)(n0 + (h) * 128 + srow) * K +                  \
                    (tile) * 64 + sc8 * 8;                                      \
    async16(&lds[BSLOT(tile, h) + w * 512], _g);                                \
    async16(&lds[BSLOT(tile, h) + 4096 + w * 512], _g + (size_t)64 * K);        \
  }

  f32x4 acc[8][4] = {};
  u16x8 bfr[4][2];

  STAGE_A0(0, 0); STAGE_A1(0); STAGE_B(0, 0); STAGE_B(0, 1); STAGE_A0(1, 1);
  asm volatile("s_waitcnt vmcnt(2)" ::: "memory");
  __builtin_amdgcn_s_barrier();
  asm volatile("" ::: "memory");
  int cur0 = 0;

  for (int T = 0; T < NT; ++T) {
    const int abase = mhalf ? A1SLOT(T) : A0SLOT(cur0);
    const int bbase = BSLOT(T, bslot_h);
#pragma unroll
    for (int q = 0; q < 4; ++q) {
      if (q == 0) {
#pragma unroll
        for (int fn = 0; fn < 4; ++fn)
#pragma unroll
          for (int ks = 0; ks < 2; ++ks)
            bfr[fn][ks] = *(const u16x8*)&lds[
                bbase + (brow0 + fn * 16 + lr) * 64 + ((ks * 32 + lg * 8) ^ rsw)];
      }
      u16x8 af[2][2];
#pragma unroll
      for (int j = 0; j < 2; ++j)
#pragma unroll
        for (int ks = 0; ks < 2; ++ks)
          af[j][ks] = *(const u16x8*)&lds[
              abase + ((q * 2 + j) * 16 + lr) * 64 + ((ks * 32 + lg * 8) ^ rsw)];
      if (q == 0) { if (T + 1 < NT) { STAGE_B(T + 1, 0); STAGE_A1(T + 1); } }
      else if (q == 1) { if (T + 1 < NT) { STAGE_B(T + 1, 1); } }
      else if (q == 2) {
        if (T + 2 < NT) {
          int s3 = cur0 + 2; if (s3 >= 3) s3 -= 3;
          STAGE_A0(T + 2, s3);
        }
      }
      if (q == 3) asm volatile("s_waitcnt vmcnt(2)" ::: "memory");
      __builtin_amdgcn_s_barrier();
      asm volatile("" ::: "memory");
      __builtin_amdgcn_s_setprio(1);
#pragma unroll
      for (int j = 0; j < 2; ++j)
#pragma unroll
        for (int fn = 0; fn < 4; ++fn)
#pragma unroll
          for (int ks = 0; ks < 2; ++ks)
            acc[q * 2 + j][fn] = __builtin_amdgcn_mfma_f32_16x16x32_bf16(
                __builtin_bit_cast(bf16x8, af[j][ks]),
                __builtin_bit_cast(bf16x8, bfr[fn][ks]), acc[q * 2 + j][fn],
                0, 0, 0);
      __builtin_amdgcn_s_setprio(0);
    }
    ++cur0; if (cur0 == 3) cur0 = 0;
  }

#pragma unroll
  for (int fm = 0; fm < 8; ++fm) {
#pragma unroll
    for (int fn = 0; fn < 4; ++fn) {
#pragma unroll
      for (int r = 0; r < 4; ++r) {
        const int row = m0 + mhalf * 128 + fm * 16 + lg * 4 + r;
        const int col = n0 + nquad * 64 + fn * 16 + lr;
        float v = acc[fm][fn][r];
        if constexpr (MODE == 1) v += bias[col];
        if constexpr (MODE == 4) v *= sigmoidf_(bf2f(gate[(size_t)row * ldg + col]));
        if constexpr (MODE == 6) {
          if (bias != nullptr) v += bias[col]; // uniform branch; full-width bias
          if (col < 2048) ((u16*)C0v)[(size_t)row * ldc + col] = f2bf(v);
          else            ((u16*)C1v)[(size_t)row * ldc + col - 2048] = f2bf(v);
        } else {
          ((u16*)C0v)[(size_t)row * ldc + col] = f2bf(v);
        }
      }
    }
  }
#undef A1SLOT
#undef A0SLOT
#undef BSLOT
#undef STAGE_A0
#undef STAGE_A1
#undef STAGE_B
}

// ---------------------------------------------------------------------------
// 128x128 GEMM. ldb = BT row stride. MODE 0: bf16; 3: +bias, softplus;
// 5: +bias, f32 store; 7: f32 partial store (split-K via blockIdx.z).
// ---------------------------------------------------------------------------
template <int MODE>
__global__ __launch_bounds__(256) void gemm_bt(
    const u16* __restrict__ A, int lda, const u16* __restrict__ BT, int ldb,
    void* __restrict__ Cv, int ldc, int K,
    const float* __restrict__ bias, const u16* __restrict__ gate, int ldg) {
  __shared__ u16 Asm[128 * 32];
  __shared__ u16 Bsm[128 * 32];
  const int m0 = blockIdx.x * 128, n0 = blockIdx.y * 128;
  if constexpr (MODE == 7) {
    const int kz = blockIdx.z;
    A += (size_t)kz * 1024;
    BT += (size_t)kz * 1024;
  }
  const int t = threadIdx.x;
  const int wave = t >> 6, lane = t & 63;
  const int wm = (wave >> 1) * 64, wn = (wave & 1) * 64;
  const int lr = lane & 15, lg = lane >> 4;
  const int sr = t >> 2, sc = (t & 3) * 8;
  const int wbase = wave * 512;
  const u16* Ap0 = A + (size_t)(m0 + sr) * lda + sc;
  const u16* Ap1 = A + (size_t)(m0 + 64 + sr) * lda + sc;
  const u16* Bp0 = BT + (size_t)(n0 + sr) * ldb + sc;
  const u16* Bp1 = BT + (size_t)(n0 + 64 + sr) * ldb + sc;

  f32x4 acc[4][4] = {};
  const int nk = K >> 5;
  for (int kt = 0; kt < nk; ++kt) {
    const int ko = kt * 32;
    __syncthreads();
    async16(&Asm[wbase], Ap0 + ko);
    async16(&Asm[2048 + wbase], Ap1 + ko);
    async16(&Bsm[wbase], Bp0 + ko);
    async16(&Bsm[2048 + wbase], Bp1 + ko);
    __syncthreads();
    u16x8 afu[4], bfu[4];
#pragma unroll
    for (int i = 0; i < 4; ++i)
      afu[i] = *(const u16x8*)&Asm[(wm + i * 16 + lr) * 32 + lg * 8];
#pragma unroll
    for (int j = 0; j < 4; ++j)
      bfu[j] = *(const u16x8*)&Bsm[(wn + j * 16 + lr) * 32 + lg * 8];
#pragma unroll
    for (int i = 0; i < 4; ++i)
#pragma unroll
      for (int j = 0; j < 4; ++j)
        acc[i][j] = __builtin_amdgcn_mfma_f32_16x16x32_bf16(
            __builtin_bit_cast(bf16x8, afu[i]), __builtin_bit_cast(bf16x8, bfu[j]),
            acc[i][j], 0, 0, 0);
  }
#pragma unroll
  for (int i = 0; i < 4; ++i) {
#pragma unroll
    for (int j = 0; j < 4; ++j) {
#pragma unroll
      for (int r = 0; r < 4; ++r) {
        const int row = m0 + wm + i * 16 + lg * 4 + r;
        const int col = n0 + wn + j * 16 + lr;
        float v = acc[i][j][r];
        if constexpr (MODE == 3 || MODE == 5) v += bias[col];
        if constexpr (MODE == 3) v = softplusf_(v);
        if constexpr (MODE == 5)
          ((float*)Cv)[(size_t)row * ldc + col] = v;
        else if constexpr (MODE == 7)
          ((float*)Cv)[(size_t)blockIdx.z * MROWS * 256 + (size_t)row * ldc + col] = v;
        else
          ((u16*)Cv)[(size_t)row * ldc + col] = f2bf(v);
      }
    }
  }
}

// ---------------------------------------------------------------------------
// Causal depthwise conv (k=4) + SiLU, vectorized: 1 thread = 8 d's.
// ---------------------------------------------------------------------------
__global__ __launch_bounds__(256) void conv_silu(
    const u16* __restrict__ xm, const float* __restrict__ cw,
    const float* __restrict__ cb, u16* __restrict__ xc) {
  const int tid = blockIdx.x * 256 + threadIdx.x; // over MROWS*DI/8
  const size_t base = (size_t)tid * 8;
  const int d8 = (int)(base & (DI - 1));
  const int row = (int)(base >> 11);
  const int s = row & (SS - 1);
  u16x8 xv[4];
#pragma unroll
  for (int j = 0; j < 4; ++j) {
    xv[j] = ((s - 3 + j) >= 0) ? *(const u16x8*)&xm[(size_t)(row - 3 + j) * DI + d8]
                               : (u16x8){0, 0, 0, 0, 0, 0, 0, 0};
  }
  u16x8 o;
#pragma unroll
  for (int dd = 0; dd < 8; ++dd) {
    f32x4 wv = *(const f32x4*)(cw + (size_t)(d8 + dd) * 4);
    float acc = cb[d8 + dd];
#pragma unroll
    for (int j = 0; j < 4; ++j)
      acc += bf2f(xv[j][dd]) * wv[j];
    float r = acc * sigmoidf_(acc);
    o[dd] = f2bf(r);
  }
  *(u16x8*)&xc[base] = o;
}

// ---------------------------------------------------------------------------
// Serial-n chunk-parallel scan; B/C read as raw f32 from dbl row tail.
// ---------------------------------------------------------------------------
__global__ __launch_bounds__(256) void scan_phaseA(
    const u16* __restrict__ delta, const u16* __restrict__ dbl,
    const u16* __restrict__ u_in,
    float* __restrict__ Pb, float* __restrict__ Sb) {
  const int t = threadIdx.x;
  const int bid = blockIdx.x;
  const int dblk = bid & 7;
  const int c = (bid >> 3) & 15;
  const int b = bid >> 7;
  const int d = dblk * 256 + t;
  const int s0 = c * CL;
  const u16* dp = delta + (size_t)(b * SS + s0) * DI + d;
  const u16* up = u_in + (size_t)(b * SS + s0) * DI + d;
  const float* bcf = (const float*)dbl + (size_t)(b * SS + s0) * 128 + 80;
  float h[16];
#pragma unroll
  for (int n = 0; n < 16; ++n) h[n] = 0.f;
  float L = 0.f;
  float dt_c = bf2f(dp[0]);
  float u_c = bf2f(up[0]);
  for (int s = 0; s < CL; ++s) {
    dp += DI; up += DI;
    float dt_n = bf2f(dp[0]); // 1-step prefetch
    float u_n = bf2f(up[0]);
    f32x4 wB[4];
#pragma unroll
    for (int i = 0; i < 4; ++i) wB[i] = *(const f32x4*)(bcf + 4 * i);
    bcf += 128;
    float e1 = __expf(-dt_c);
    float dtu = dt_c * u_c;
    L += dt_c;
    float e = 1.f;
#pragma unroll
    for (int i = 0; i < 4; ++i) {
#pragma unroll
      for (int k = 0; k < 4; ++k) {
        e *= e1;
        h[4 * i + k] = fmaf(e, h[4 * i + k], dtu * wB[i][k]);
      }
    }
    dt_c = dt_n; u_c = u_n;
  }
  const float E = __expf(-L);
  const size_t base = (((size_t)(b * DI + d)) * 16) * NCH + c;
  float P = 1.f;
#pragma unroll
  for (int n = 0; n < 16; ++n) {
    P *= E;
    Pb[base + (size_t)n * NCH] = P;
    Sb[base + (size_t)n * NCH] = h[n];
  }
}

__global__ __launch_bounds__(256) void scan_phaseB(
    const float* __restrict__ Pb, const float* __restrict__ Sb,
    float* __restrict__ Hb) {
  const size_t tid = (size_t)blockIdx.x * 256 + threadIdx.x;
  const size_t base = tid * NCH;
  float h = 0.f;
#pragma unroll
  for (int cc = 0; cc < NCH; ++cc) {
    Hb[base + cc] = h;
    h = Sb[base + cc] + Pb[base + cc] * h;
  }
}

__global__ __launch_bounds__(256) void scan_phaseC(
    const u16* __restrict__ delta, const u16* __restrict__ dbl,
    const u16* __restrict__ u_in, u16* __restrict__ zy,
    const float* __restrict__ D_skip, const float* __restrict__ Hb) {
  const int t = threadIdx.x;
  const int bid = blockIdx.x;
  const int dblk = bid & 7;
  const int c = (bid >> 3) & 15;
  const int b = bid >> 7;
  const int d = dblk * 256 + t;
  const float Dsk = D_skip[d];
  const size_t hbase = (((size_t)(b * DI + d)) * 16) * NCH + c;
  float h[16];
#pragma unroll
  for (int n = 0; n < 16; ++n) h[n] = Hb[hbase + (size_t)n * NCH];
  const int s0 = c * CL;
  const u16* dp = delta + (size_t)(b * SS + s0) * DI + d;
  const u16* up = u_in + (size_t)(b * SS + s0) * DI + d;
  u16* zp = zy + (size_t)(b * SS + s0) * DI + d;
  const float* bcf = (const float*)dbl + (size_t)(b * SS + s0) * 128 + 80;
  float dt_c = bf2f(dp[0]);
  float u_c = bf2f(up[0]);
  float z_c = bf2f(zp[0]);
  for (int s = 0; s < CL; ++s) {
    dp += DI; up += DI;
    float dt_n = bf2f(dp[0]); // 1-step prefetch
    float u_n = bf2f(up[0]);
    float z_n = bf2f(zp[DI]);
    f32x4 wB[4], wC[4];
#pragma unroll
    for (int i = 0; i < 4; ++i) {
      wB[i] = *(const f32x4*)(bcf + 4 * i);
      wC[i] = *(const f32x4*)(bcf + 16 + 4 * i);
    }
    bcf += 128;
    float e1 = __expf(-dt_c);
    float dtu = dt_c * u_c;
    float e = 1.f, y = 0.f;
#pragma unroll
    for (int i = 0; i < 4; ++i) {
#pragma unroll
      for (int k = 0; k < 4; ++k) {
        e *= e1;
        h[4 * i + k] = fmaf(e, h[4 * i + k], dtu * wB[i][k]);
        y = fmaf(h[4 * i + k], wC[i][k], y);
      }
    }
    float yo = (y + Dsk * u_c) * (z_c * sigmoidf_(z_c));
    zp[0] = f2bf(yo);
    zp += DI;
    dt_c = dt_n; u_c = u_n; z_c = z_n;
  }
}

// ---------------------------------------------------------------------------
extern "C" void kernel_launch(void* const* d_in, const int* in_sizes, int n_in,
                              void* d_out, int out_size, void* d_ws, size_t ws_size,
                              hipStream_t stream) {
  const float* x       = (const float*)d_in[0];
  const float* W_in_o  = (const float*)d_in[1];
  const float* b_in_o  = (const float*)d_in[2];
  const float* W_out_o = (const float*)d_in[3];
  const float* b_out_o = (const float*)d_in[4];
  const float* W_in_i  = (const float*)d_in[5];
  const float* conv_w  = (const float*)d_in[6];
  const float* conv_b  = (const float*)d_in[7];
  const float* W_xp    = (const float*)d_in[8];
  const float* W_dt    = (const float*)d_in[9];
  const float* b_dt    = (const float*)d_in[10];
  const float* D_skip  = (const float*)d_in[12];
  const float* W_out_i = (const float*)d_in[13];
  float* out = (float*)d_out;
  char* ws = (char*)d_ws;

  const size_t SLOT = (size_t)MROWS * DI * 2; // 32 MiB
  const size_t o_A = 0, o_B = SLOT, o_C = 2 * SLOT, o_E = 3 * SLOT;
  const size_t o_F = 4 * SLOT;
  const size_t tail4 = 4 * SLOT, tail5 = 5 * SLOT;
  const size_t need4 = tail4 + (size_t)MROWS * 256 * 2 + (size_t)2048 * 128 * 2;
  const size_t need5 = tail5 + (size_t)MROWS * 256 * 2 + (size_t)2048 * 128 * 2;
  if (need4 > ws_size) return;
  const bool five = (need5 <= ws_size);
  const size_t o_dbl = five ? tail5 : tail4;
  const size_t o_wdt = o_dbl + (size_t)MROWS * 256 * 2;

  u16* Abuf = (u16*)(ws + o_A);
  u16* Bbuf = (u16*)(ws + o_B);
  u16* Cbuf = (u16*)(ws + o_C);
  u16* Ebuf = (u16*)(ws + o_E);
  u16* Fbuf = (u16*)(ws + o_F);
  u16* dbl  = (u16*)(ws + o_dbl);
  u16* wdt  = (u16*)(ws + o_wdt);
  float* Pb = (float*)(ws + o_B);
  float* Sb = Pb + (size_t)2097152;
  float* Hb = Sb + (size_t)2097152;
  float* g3part = (float*)(ws + o_B);

  if (five) {
    // ----- Path A: fused G1, bias in MODE-6 epilogue (no bias_add pass) ----
    u16* wio = Ebuf;              // 4096 x 1024 (8 MiB)
    u16* wii = Ebuf + 4194304;    // 4096 x 2048 (16 MiB)
    u16* wxp = Ebuf + 12582912;   // 256 x 2048  (1 MiB)
    u16* woi = Bbuf;              // post-scan reuse of B
    u16* woo = Bbuf + 4194304;

    cvt_bf16<<<(MROWS * 1024 / 4 + 255) / 256, 256, 0, stream>>>(x, Bbuf, MROWS * 1024 / 4);
    {
      TBatch tb1;
      tb1.n = 5;
      tb1.d[0] = { W_in_o, wio, 1024, 4096, 0, 4096, 4096 };
      tb1.d[1] = { W_in_i, wii, 2048, 4096, 0, 2048, 2048 };
      tb1.d[2] = { W_in_i, wii + (size_t)2048 * 2048, 2048, 4096, 2048, 2048, 2048 };
      tb1.d[3] = { W_xp, wxp, 2048, 160, 0, 160, 256 };
      tb1.d[4] = { W_dt, wdt, 128, 2048, 0, 2048, 2048 };
      transpose_batch<<<dim3(64, 128, 5), dim3(32, 8), 0, stream>>>(tb1);
    }
    // G1 fused: xp|zp = x_bf @ wio + b_in_o (split xp->A, zp->F)
    gemm256<6><<<dim3(32, 16), 512, 0, stream>>>(Bbuf, 1024, wio, Abuf, Fbuf, 2048, 1024, b_in_o, nullptr, 0);
    // G2: xm|zm = xp @ wii (no bias)
    gemm256<6><<<dim3(32, 16), 512, 0, stream>>>(Abuf, 2048, wii, Bbuf, Cbuf, 2048, 2048, nullptr, nullptr, 0);
    conv_silu<<<(MROWS * DI / 8) / 256, 256, 0, stream>>>(Bbuf, conv_w, conv_b, Abuf);
    gemm_bt<7><<<dim3(64, 2, 2), 256, 0, stream>>>(Abuf, 2048, wxp, 2048, g3part, 256, 1024, nullptr, nullptr, 0);
    combine_dbl<<<(MROWS * 256 / 4 + 255) / 256, 256, 0, stream>>>(g3part, dbl, MROWS * 256 / 4);
    gemm_bt<3><<<dim3(64, 16), 256, 0, stream>>>(dbl, 256, wdt, 128, Ebuf, 2048, 128, b_dt, nullptr, 0);
    scan_phaseA<<<BB * NCH * 8, 256, 0, stream>>>(Ebuf, dbl, Abuf, Pb, Sb);
    scan_phaseB<<<512, 256, 0, stream>>>(Pb, Sb, Hb);
    scan_phaseC<<<BB * NCH * 8, 256, 0, stream>>>(Ebuf, dbl, Abuf, Cbuf, D_skip, Hb);
    {
      TBatch tb2;
      tb2.n = 2;
      tb2.d[0] = { W_out_i, woi, 2048, 2048, 0, 2048, 2048 };
      tb2.d[1] = { W_out_o, woo, 2048, 1024, 0, 1024, 1024 };
      tb2.d[2] = { nullptr, nullptr, 0, 0, 0, 0, 0 };
      tb2.d[3] = { nullptr, nullptr, 0, 0, 0, 0, 0 };
      tb2.d[4] = { nullptr, nullptr, 0, 0, 0, 0, 0 };
      transpose_batch<<<dim3(64, 64, 2), dim3(32, 8), 0, stream>>>(tb2);
    }
    // G5: o2 = (yg @ woi) * sigmoid(zp in F)
    gemm256<4><<<dim3(32, 8), 512, 0, stream>>>(Cbuf, 2048, woi, Abuf, nullptr, 2048, 2048, nullptr, Fbuf, 2048);
    gemm_bt<5><<<dim3(64, 8), 256, 0, stream>>>(Abuf, 2048, woo, 2048, out, 1024, 2048, b_out_o, nullptr, 0);
  } else {
    // ----- Path B: exact round-18 sequence -----
    u16* wio_a = Ebuf;
    u16* wii   = Ebuf + 2097152;
    u16* wxp   = Ebuf + 10485760;
    u16* wio_b = Bbuf;
    u16* woi   = Bbuf + 2097152;
    u16* woo   = Bbuf + 6291456;
    u16* xbf2  = Bbuf + 8388608;

    cvt_bf16<<<(MROWS * 1024 / 4 + 255) / 256, 256, 0, stream>>>(x, Bbuf, MROWS * 1024 / 4);
    {
      TBatch tb1;
      tb1.n = 5;
      tb1.d[0] = { W_in_o, wio_a, 1024, 4096, 0, 2048, 2048 };
      tb1.d[1] = { W_in_i, wii, 2048, 4096, 0, 2048, 2048 };
      tb1.d[2] = { W_in_i, wii + (size_t)2048 * 2048, 2048, 4096, 2048, 2048, 2048 };
      tb1.d[3] = { W_xp, wxp, 2048, 160, 0, 160, 256 };
      tb1.d[4] = { W_dt, wdt, 128, 2048, 0, 2048, 2048 };
      transpose_batch<<<dim3(64, 64, 5), dim3(32, 8), 0, stream>>>(tb1);
    }
    gemm256<1><<<dim3(32, 8), 512, 0, stream>>>(Bbuf, 1024, wio_a, Abuf, nullptr, 2048, 1024, b_in_o, nullptr, 0);
    gemm256<6><<<dim3(32, 16), 512, 0, stream>>>(Abuf, 2048, wii, Bbuf, Cbuf, 2048, 2048, nullptr, nullptr, 0);
    conv_silu<<<(MROWS * DI / 8) / 256, 256, 0, stream>>>(Bbuf, conv_w, conv_b, Abuf);
    gemm_bt<7><<<dim3(64, 2, 2), 256, 0, stream>>>(Abuf, 2048, wxp, 2048, g3part, 256, 1024, nullptr, nullptr, 0);
    combine_dbl<<<(MROWS * 256 / 4 + 255) / 256, 256, 0, stream>>>(g3part, dbl, MROWS * 256 / 4);
    gemm_bt<3><<<dim3(64, 16), 256, 0, stream>>>(dbl, 256, wdt, 128, Ebuf, 2048, 128, b_dt, nullptr, 0);
    scan_phaseA<<<BB * NCH * 8, 256, 0, stream>>>(Ebuf, dbl, Abuf, Pb, Sb);
    scan_phaseB<<<512, 256, 0, stream>>>(Pb, Sb, Hb);
    scan_phaseC<<<BB * NCH * 8, 256, 0, stream>>>(Ebuf, dbl, Abuf, Cbuf, D_skip, Hb);
    cvt_bf16<<<(MROWS * 1024 / 4 + 255) / 256, 256, 0, stream>>>(x, xbf2, MROWS * 1024 / 4);
    {
      TBatch tb2;
      tb2.n = 3;
      tb2.d[0] = { W_in_o, wio_b, 1024, 4096, 2048, 2048, 2048 };
      tb2.d[1] = { W_out_i, woi, 2048, 2048, 0, 2048, 2048 };
      tb2.d[2] = { W_out_o, woo, 2048, 1024, 0, 1024, 1024 };
      tb2.d[3] = { nullptr, nullptr, 0, 0, 0, 0, 0 };
      tb2.d[4] = { nullptr, nullptr, 0, 0, 0, 0, 0 };
      transpose_batch<<<dim3(64, 64, 3), dim3(32, 8), 0, stream>>>(tb2);
    }
    gemm256<1><<<dim3(32, 8), 512, 0, stream>>>(xbf2, 1024, wio_b, Ebuf, nullptr, 2048, 1024, b_in_o + 2048, nullptr, 0);
    gemm256<4><<<dim3(32, 8), 512, 0, stream>>>(Cbuf, 2048, woi, Abuf, nullptr, 2048, 2048, nullptr, Ebuf, 2048);
    gemm_bt<5><<<dim3(64, 8), 256, 0, stream>>>(Abuf, 2048, woo, 2048, out, 1024, 2048, b_out_o, nullptr, 0);
  }
}

// Round 21
// 634.557 us; speedup vs baseline: 1.0384x; 1.0356x over previous
//
#include <hip/hip_runtime.h>
#include <stdint.h>
#include <math.h>

// ---------------------------------------------------------------------------
// SimpleMamba2Like on MI355X — Round 21: r20's fused-G1 with the bias as a
// COMPILE-TIME variant (MODE 8 = split store + bias). MODE 6 reverts to the
// exact r18 epilogue (no bias pointer, no runtime branch) — r20's 3.5%
// slowdown on every MODE-6 dispatch is undone. Path A: fused G1 (MODE 8,
// xp->A, zp->F persists to G5), one cvt_bf16, merged transposes. Path B
// fallback = exact round-18 sequence. All other kernels identical to r18.
// ---------------------------------------------------------------------------

typedef unsigned short u16;
typedef __bf16 bf16x8 __attribute__((ext_vector_type(8)));
typedef u16 u16x8 __attribute__((ext_vector_type(8)));
typedef u16 u16x4 __attribute__((ext_vector_type(4)));
typedef float f32x4 __attribute__((ext_vector_type(4)));

static constexpr int BB = 4, SS = 2048, DI = 2048, DST = 16, DTR = 128;
static constexpr int MROWS = BB * SS; // 8192
static constexpr int NCH = 16, CL = 128;

__device__ __forceinline__ float bf2f(u16 x) {
  union { unsigned u; float f; } v; v.u = ((unsigned)x) << 16; return v.f;
}
__device__ __forceinline__ u16 f2bf(float f) {
  union { float f; unsigned u; } v; v.f = f;
  unsigned r = (v.u + 0x7FFFu + ((v.u >> 16) & 1u)) >> 16; // RNE
  return (u16)r;
}
__device__ __forceinline__ float sigmoidf_(float x) { return 1.f / (1.f + __expf(-x)); }
__device__ __forceinline__ float softplusf_(float x) {
  return fmaxf(x, 0.f) + log1pf(__expf(-fabsf(x)));
}
__device__ __forceinline__ void async16(u16* lds, const u16* g) {
  __builtin_amdgcn_global_load_lds(
      (__attribute__((address_space(1))) void*)g,
      (__attribute__((address_space(3))) void*)lds, 16, 0, 0);
}

// ---------------------------------------------------------------------------
__global__ __launch_bounds__(256) void cvt_bf16(const float* __restrict__ in,
                                                u16* __restrict__ out, int n4) {
  const int i = blockIdx.x * 256 + threadIdx.x;
  if (i >= n4) return;
  f32x4 v = *(const f32x4*)(in + (size_t)i * 4);
  u16x4 o = { f2bf(v[0]), f2bf(v[1]), f2bf(v[2]), f2bf(v[3]) };
  *(u16x4*)(out + (size_t)i * 4) = o;
}

// ---------------------------------------------------------------------------
// Combine G3 split-K partials. cols<128 -> bf16 dt; cols 128..159 -> ALSO
// raw f32 packed at dbl row-tail bytes [320,448).
// ---------------------------------------------------------------------------
__global__ __launch_bounds__(256) void combine_dbl(const float* __restrict__ P,
                                                   u16* __restrict__ dbl, int n4) {
  const int i = blockIdx.x * 256 + threadIdx.x;
  if (i >= n4) return;
  const float* P1 = P + (size_t)MROWS * 256;
  f32x4 a = *(const f32x4*)(P + (size_t)i * 4);
  f32x4 b = *(const f32x4*)(P1 + (size_t)i * 4);
  f32x4 s = { a[0] + b[0], a[1] + b[1], a[2] + b[2], a[3] + b[3] };
  const int col = (i * 4) & 255;
  const int row = (i * 4) >> 8;
  if (col < 128) {
    u16x4 o = { f2bf(s[0]), f2bf(s[1]), f2bf(s[2]), f2bf(s[3]) };
    *(u16x4*)&dbl[(size_t)row * 256 + col] = o;
  } else if (col < 160) {
    float* fp = (float*)dbl + (size_t)row * 128 + 80 + (col - 128);
    *(f32x4*)fp = s;
  }
}

// ---------------------------------------------------------------------------
// Batched transpose. blockIdx.z selects a descriptor.
// ---------------------------------------------------------------------------
struct TDesc {
  const float* in;
  u16* out;
  int K, N_full, n_off, N_sub, Npad;
};
struct TBatch { TDesc d[5]; int n; };

__global__ void transpose_batch(TBatch batch) {
  if ((int)blockIdx.z >= batch.n) return;
  const TDesc dd = batch.d[blockIdx.z];
  const int k0 = blockIdx.x * 32, n0 = blockIdx.y * 32;
  if (k0 >= dd.K || n0 >= dd.Npad) return; // block-uniform exit (pre-LDS)
  __shared__ u16 tile[32][33];
  const int tx = threadIdx.x, ty = threadIdx.y; // 32 x 8
#pragma unroll
  for (int i = 0; i < 4; ++i) {
    int k = k0 + ty + i * 8, nn = n0 + tx;
    tile[ty + i * 8][tx] =
        (k < dd.K && nn < dd.N_sub)
            ? f2bf(dd.in[(size_t)k * dd.N_full + dd.n_off + nn]) : (u16)0;
  }
  __syncthreads();
#pragma unroll
  for (int i = 0; i < 4; ++i) {
    int nn = n0 + ty + i * 8, k = k0 + tx;
    if (nn < dd.Npad && k < dd.K) dd.out[(size_t)nn * dd.K + k] = tile[tx][ty + i * 8];
  }
}

// ---------------------------------------------------------------------------
// 256x256-tile GEMM (r14 schedule): T2-swizzled LDS, wave layout 2M x 4N,
// one counted vmcnt(2) per K-tile (q3), one barrier per phase.
// MODE 1: +bias, bf16       MODE 4: *sigmoid(gate), bf16
// MODE 6: split store (col<2048 -> C0 else C1), NO bias (r18-identical)
// MODE 8: split store + bias[col] (full 4096-wide), compile-time variant
// ---------------------------------------------------------------------------
template <int MODE>
__global__ __launch_bounds__(512, 1) void gemm256(
    const u16* __restrict__ A, int lda, const u16* __restrict__ BT,
    void* __restrict__ C0v, void* __restrict__ C1v, int ldc, int K,
    const float* __restrict__ bias, const u16* __restrict__ gate, int ldg) {
  __shared__ u16 lds[73728]; // 144 KiB
  const int m0 = blockIdx.x * 256, n0 = blockIdx.y * 256;
  const int t = threadIdx.x, w = t >> 6, l = t & 63;
  const int lr = l & 15, lg = l >> 4;
  const int mhalf = w >> 2, nquad = w & 3;
  const int bslot_h = nquad >> 1, brow0 = (nquad & 1) * 64;
  const int NT = K >> 6;
  const int srow = t >> 3;
  const int sc8 = (t & 7) ^ (srow & 7); // T2: inverse-swizzled source col
  const int rsw = (lr & 7) << 3;        // T2: element-XOR for ds_read

#define A1SLOT(tile) ((((tile) & 1)) * 8192)
#define A0SLOT(s3) (16384 + (s3) * 8192)
#define BSLOT(tile, h) (40960 + (((tile) & 1) * 2 + (h)) * 8192)
#define STAGE_A0(tile, s3)                                                      \
  {                                                                             \
    const u16* _g = A + (size_t)(m0 + srow) * lda + (tile) * 64 + sc8 * 8;      \
    async16(&lds[A0SLOT(s3) + w * 512], _g);                                    \
    async16(&lds[A0SLOT(s3) + 4096 + w * 512], _g + (size_t)64 * lda);          \
  }
#define STAGE_A1(tile)                                                          \
  {                                                                             \
    const u16* _g = A + (size_t)(m0 + 128 + srow) * lda + (tile) * 64 + sc8 * 8;\
    async16(&lds[A1SLOT(tile) + w * 512], _g);                                  \
    async16(&lds[A1SLOT(tile) + 4096 + w * 512], _g + (size_t)64 * lda);        \
  }
#define STAGE_B(tile, h)                                                        \
  {                                                                             \
    const u16* _g = BT + (size_t)(n0 + (h) * 128 + srow) * K +                  \
                    (tile) * 64 + sc8 * 8;                                      \
    async16(&lds[BSLOT(tile, h) + w * 512], _g);                                \
    async16(&lds[BSLOT(tile, h) + 4096 + w * 512], _g + (size_t)64 * K);        \
  }

  f32x4 acc[8][4] = {};
  u16x8 bfr[4][2];

  STAGE_A0(0, 0); STAGE_A1(0); STAGE_B(0, 0); STAGE_B(0, 1); STAGE_A0(1, 1);
  asm volatile("s_waitcnt vmcnt(2)" ::: "memory");
  __builtin_amdgcn_s_barrier();
  asm volatile("" ::: "memory");
  int cur0 = 0;

  for (int T = 0; T < NT; ++T) {
    const int abase = mhalf ? A1SLOT(T) : A0SLOT(cur0);
    const int bbase = BSLOT(T, bslot_h);
#pragma unroll
    for (int q = 0; q < 4; ++q) {
      if (q == 0) {
#pragma unroll
        for (int fn = 0; fn < 4; ++fn)
#pragma unroll
          for (int ks = 0; ks < 2; ++ks)
            bfr[fn][ks] = *(const u16x8*)&lds[
                bbase + (brow0 + fn * 16 + lr) * 64 + ((ks * 32 + lg * 8) ^ rsw)];
      }
      u16x8 af[2][2];
#pragma unroll
      for (int j = 0; j < 2; ++j)
#pragma unroll
        for (int ks = 0; ks < 2; ++ks)
          af[j][ks] = *(const u16x8*)&lds[
              abase + ((q * 2 + j) * 16 + lr) * 64 + ((ks * 32 + lg * 8) ^ rsw)];
      if (q == 0) { if (T + 1 < NT) { STAGE_B(T + 1, 0); STAGE_A1(T + 1); } }
      else if (q == 1) { if (T + 1 < NT) { STAGE_B(T + 1, 1); } }
      else if (q == 2) {
        if (T + 2 < NT) {
          int s3 = cur0 + 2; if (s3 >= 3) s3 -= 3;
          STAGE_A0(T + 2, s3);
        }
      }
      if (q == 3) asm volatile("s_waitcnt vmcnt(2)" ::: "memory");
      __builtin_amdgcn_s_barrier();
      asm volatile("" ::: "memory");
      __builtin_amdgcn_s_setprio(1);
#pragma unroll
      for (int j = 0; j < 2; ++j)
#pragma unroll
        for (int fn = 0; fn < 4; ++fn)
#pragma unroll
          for (int ks = 0; ks < 2; ++ks)
            acc[q * 2 + j][fn] = __builtin_amdgcn_mfma_f32_16x16x32_bf16(
                __builtin_bit_cast(bf16x8, af[j][ks]),
                __builtin_bit_cast(bf16x8, bfr[fn][ks]), acc[q * 2 + j][fn],
                0, 0, 0);
      __builtin_amdgcn_s_setprio(0);
    }
    ++cur0; if (cur0 == 3) cur0 = 0;
  }

#pragma unroll
  for (int fm = 0; fm < 8; ++fm) {
#pragma unroll
    for (int fn = 0; fn < 4; ++fn) {
#pragma unroll
      for (int r = 0; r < 4; ++r) {
        const int row = m0 + mhalf * 128 + fm * 16 + lg * 4 + r;
        const int col = n0 + nquad * 64 + fn * 16 + lr;
        float v = acc[fm][fn][r];
        if constexpr (MODE == 1 || MODE == 8) v += bias[col];
        if constexpr (MODE == 4) v *= sigmoidf_(bf2f(gate[(size_t)row * ldg + col]));
        if constexpr (MODE == 6 || MODE == 8) {
          if (col < 2048) ((u16*)C0v)[(size_t)row * ldc + col] = f2bf(v);
          else            ((u16*)C1v)[(size_t)row * ldc + col - 2048] = f2bf(v);
        } else {
          ((u16*)C0v)[(size_t)row * ldc + col] = f2bf(v);
        }
      }
    }
  }
#undef A1SLOT
#undef A0SLOT
#undef BSLOT
#undef STAGE_A0
#undef STAGE_A1
#undef STAGE_B
}

// ---------------------------------------------------------------------------
// 128x128 GEMM. ldb = BT row stride. MODE 0: bf16; 3: +bias, softplus;
// 5: +bias, f32 store; 7: f32 partial store (split-K via blockIdx.z).
// ---------------------------------------------------------------------------
template <int MODE>
__global__ __launch_bounds__(256) void gemm_bt(
    const u16* __restrict__ A, int lda, const u16* __restrict__ BT, int ldb,
    void* __restrict__ Cv, int ldc, int K,
    const float* __restrict__ bias, const u16* __restrict__ gate, int ldg) {
  __shared__ u16 Asm[128 * 32];
  __shared__ u16 Bsm[128 * 32];
  const int m0 = blockIdx.x * 128, n0 = blockIdx.y * 128;
  if constexpr (MODE == 7) {
    const int kz = blockIdx.z;
    A += (size_t)kz * 1024;
    BT += (size_t)kz * 1024;
  }
  const int t = threadIdx.x;
  const int wave = t >> 6, lane = t & 63;
  const int wm = (wave >> 1) * 64, wn = (wave & 1) * 64;
  const int lr = lane & 15, lg = lane >> 4;
  const int sr = t >> 2, sc = (t & 3) * 8;
  const int wbase = wave * 512;
  const u16* Ap0 = A + (size_t)(m0 + sr) * lda + sc;
  const u16* Ap1 = A + (size_t)(m0 + 64 + sr) * lda + sc;
  const u16* Bp0 = BT + (size_t)(n0 + sr) * ldb + sc;
  const u16* Bp1 = BT + (size_t)(n0 + 64 + sr) * ldb + sc;

  f32x4 acc[4][4] = {};
  const int nk = K >> 5;
  for (int kt = 0; kt < nk; ++kt) {
    const int ko = kt * 32;
    __syncthreads();
    async16(&Asm[wbase], Ap0 + ko);
    async16(&Asm[2048 + wbase], Ap1 + ko);
    async16(&Bsm[wbase], Bp0 + ko);
    async16(&Bsm[2048 + wbase], Bp1 + ko);
    __syncthreads();
    u16x8 afu[4], bfu[4];
#pragma unroll
    for (int i = 0; i < 4; ++i)
      afu[i] = *(const u16x8*)&Asm[(wm + i * 16 + lr) * 32 + lg * 8];
#pragma unroll
    for (int j = 0; j < 4; ++j)
      bfu[j] = *(const u16x8*)&Bsm[(wn + j * 16 + lr) * 32 + lg * 8];
#pragma unroll
    for (int i = 0; i < 4; ++i)
#pragma unroll
      for (int j = 0; j < 4; ++j)
        acc[i][j] = __builtin_amdgcn_mfma_f32_16x16x32_bf16(
            __builtin_bit_cast(bf16x8, afu[i]), __builtin_bit_cast(bf16x8, bfu[j]),
            acc[i][j], 0, 0, 0);
  }
#pragma unroll
  for (int i = 0; i < 4; ++i) {
#pragma unroll
    for (int j = 0; j < 4; ++j) {
#pragma unroll
      for (int r = 0; r < 4; ++r) {
        const int row = m0 + wm + i * 16 + lg * 4 + r;
        const int col = n0 + wn + j * 16 + lr;
        float v = acc[i][j][r];
        if constexpr (MODE == 3 || MODE == 5) v += bias[col];
        if constexpr (MODE == 3) v = softplusf_(v);
        if constexpr (MODE == 5)
          ((float*)Cv)[(size_t)row * ldc + col] = v;
        else if constexpr (MODE == 7)
          ((float*)Cv)[(size_t)blockIdx.z * MROWS * 256 + (size_t)row * ldc + col] = v;
        else
          ((u16*)Cv)[(size_t)row * ldc + col] = f2bf(v);
      }
    }
  }
}

// ---------------------------------------------------------------------------
// Causal depthwise conv (k=4) + SiLU, vectorized: 1 thread = 8 d's.
// ---------------------------------------------------------------------------
__global__ __launch_bounds__(256) void conv_silu(
    const u16* __restrict__ xm, const float* __restrict__ cw,
    const float* __restrict__ cb, u16* __restrict__ xc) {
  const int tid = blockIdx.x * 256 + threadIdx.x; // over MROWS*DI/8
  const size_t base = (size_t)tid * 8;
  const int d8 = (int)(base & (DI - 1));
  const int row = (int)(base >> 11);
  const int s = row & (SS - 1);
  u16x8 xv[4];
#pragma unroll
  for (int j = 0; j < 4; ++j) {
    xv[j] = ((s - 3 + j) >= 0) ? *(const u16x8*)&xm[(size_t)(row - 3 + j) * DI + d8]
                               : (u16x8){0, 0, 0, 0, 0, 0, 0, 0};
  }
  u16x8 o;
#pragma unroll
  for (int dd = 0; dd < 8; ++dd) {
    f32x4 wv = *(const f32x4*)(cw + (size_t)(d8 + dd) * 4);
    float acc = cb[d8 + dd];
#pragma unroll
    for (int j = 0; j < 4; ++j)
      acc += bf2f(xv[j][dd]) * wv[j];
    float r = acc * sigmoidf_(acc);
    o[dd] = f2bf(r);
  }
  *(u16x8*)&xc[base] = o;
}

// ---------------------------------------------------------------------------
// Serial-n chunk-parallel scan; B/C read as raw f32 from dbl row tail.
// ---------------------------------------------------------------------------
__global__ __launch_bounds__(256) void scan_phaseA(
    const u16* __restrict__ delta, const u16* __restrict__ dbl,
    const u16* __restrict__ u_in,
    float* __restrict__ Pb, float* __restrict__ Sb) {
  const int t = threadIdx.x;
  const int bid = blockIdx.x;
  const int dblk = bid & 7;
  const int c = (bid >> 3) & 15;
  const int b = bid >> 7;
  const int d = dblk * 256 + t;
  const int s0 = c * CL;
  const u16* dp = delta + (size_t)(b * SS + s0) * DI + d;
  const u16* up = u_in + (size_t)(b * SS + s0) * DI + d;
  const float* bcf = (const float*)dbl + (size_t)(b * SS + s0) * 128 + 80;
  float h[16];
#pragma unroll
  for (int n = 0; n < 16; ++n) h[n] = 0.f;
  float L = 0.f;
  float dt_c = bf2f(dp[0]);
  float u_c = bf2f(up[0]);
  for (int s = 0; s < CL; ++s) {
    dp += DI; up += DI;
    float dt_n = bf2f(dp[0]); // 1-step prefetch
    float u_n = bf2f(up[0]);
    f32x4 wB[4];
#pragma unroll
    for (int i = 0; i < 4; ++i) wB[i] = *(const f32x4*)(bcf + 4 * i);
    bcf += 128;
    float e1 = __expf(-dt_c);
    float dtu = dt_c * u_c;
    L += dt_c;
    float e = 1.f;
#pragma unroll
    for (int i = 0; i < 4; ++i) {
#pragma unroll
      for (int k = 0; k < 4; ++k) {
        e *= e1;
        h[4 * i + k] = fmaf(e, h[4 * i + k], dtu * wB[i][k]);
      }
    }
    dt_c = dt_n; u_c = u_n;
  }
  const float E = __expf(-L);
  const size_t base = (((size_t)(b * DI + d)) * 16) * NCH + c;
  float P = 1.f;
#pragma unroll
  for (int n = 0; n < 16; ++n) {
    P *= E;
    Pb[base + (size_t)n * NCH] = P;
    Sb[base + (size_t)n * NCH] = h[n];
  }
}

__global__ __launch_bounds__(256) void scan_phaseB(
    const float* __restrict__ Pb, const float* __restrict__ Sb,
    float* __restrict__ Hb) {
  const size_t tid = (size_t)blockIdx.x * 256 + threadIdx.x;
  const size_t base = tid * NCH;
  float h = 0.f;
#pragma unroll
  for (int cc = 0; cc < NCH; ++cc) {
    Hb[base + cc] = h;
    h = Sb[base + cc] + Pb[base + cc] * h;
  }
}

__global__ __launch_bounds__(256) void scan_phaseC(
    const u16* __restrict__ delta, const u16* __restrict__ dbl,
    const u16* __restrict__ u_in, u16* __restrict__ zy,
    const float* __restrict__ D_skip, const float* __restrict__ Hb) {
  const int t = threadIdx.x;
  const int bid = blockIdx.x;
  const int dblk = bid & 7;
  const int c = (bid >> 3) & 15;
  const int b = bid >> 7;
  const int d = dblk * 256 + t;
  const float Dsk = D_skip[d];
  const size_t hbase = (((size_t)(b * DI + d)) * 16) * NCH + c;
  float h[16];
#pragma unroll
  for (int n = 0; n < 16; ++n) h[n] = Hb[hbase + (size_t)n * NCH];
  const int s0 = c * CL;
  const u16* dp = delta + (size_t)(b * SS + s0) * DI + d;
  const u16* up = u_in + (size_t)(b * SS + s0) * DI + d;
  u16* zp = zy + (size_t)(b * SS + s0) * DI + d;
  const float* bcf = (const float*)dbl + (size_t)(b * SS + s0) * 128 + 80;
  float dt_c = bf2f(dp[0]);
  float u_c = bf2f(up[0]);
  float z_c = bf2f(zp[0]);
  for (int s = 0; s < CL; ++s) {
    dp += DI; up += DI;
    float dt_n = bf2f(dp[0]); // 1-step prefetch
    float u_n = bf2f(up[0]);
    float z_n = bf2f(zp[DI]);
    f32x4 wB[4], wC[4];
#pragma unroll
    for (int i = 0; i < 4; ++i) {
      wB[i] = *(const f32x4*)(bcf + 4 * i);
      wC[i] = *(const f32x4*)(bcf + 16 + 4 * i);
    }
    bcf += 128;
    float e1 = __expf(-dt_c);
    float dtu = dt_c * u_c;
    float e = 1.f, y = 0.f;
#pragma unroll
    for (int i = 0; i < 4; ++i) {
#pragma unroll
      for (int k = 0; k < 4; ++k) {
        e *= e1;
        h[4 * i + k] = fmaf(e, h[4 * i + k], dtu * wB[i][k]);
        y = fmaf(h[4 * i + k], wC[i][k], y);
      }
    }
    float yo = (y + Dsk * u_c) * (z_c * sigmoidf_(z_c));
    zp[0] = f2bf(yo);
    zp += DI;
    dt_c = dt_n; u_c = u_n; z_c = z_n;
  }
}

// ---------------------------------------------------------------------------
extern "C" void kernel_launch(void* const* d_in, const int* in_sizes, int n_in,
                              void* d_out, int out_size, void* d_ws, size_t ws_size,
                              hipStream_t stream) {
  const float* x       = (const float*)d_in[0];
  const float* W_in_o  = (const float*)d_in[1];
  const float* b_in_o  = (const float*)d_in[2];
  const float* W_out_o = (const float*)d_in[3];
  const float* b_out_o = (const float*)d_in[4];
  const float* W_in_i  = (const float*)d_in[5];
  const float* conv_w  = (const float*)d_in[6];
  const float* conv_b  = (const float*)d_in[7];
  const float* W_xp    = (const float*)d_in[8];
  const float* W_dt    = (const float*)d_in[9];
  const float* b_dt    = (const float*)d_in[10];
  const float* D_skip  = (const float*)d_in[12];
  const float* W_out_i = (const float*)d_in[13];
  float* out = (float*)d_out;
  char* ws = (char*)d_ws;

  const size_t SLOT = (size_t)MROWS * DI * 2; // 32 MiB
  const size_t o_A = 0, o_B = SLOT, o_C = 2 * SLOT, o_E = 3 * SLOT;
  const size_t o_F = 4 * SLOT;
  const size_t tail4 = 4 * SLOT, tail5 = 5 * SLOT;
  const size_t need4 = tail4 + (size_t)MROWS * 256 * 2 + (size_t)2048 * 128 * 2;
  const size_t need5 = tail5 + (size_t)MROWS * 256 * 2 + (size_t)2048 * 128 * 2;
  if (need4 > ws_size) return;
  const bool five = (need5 <= ws_size);
  const size_t o_dbl = five ? tail5 : tail4;
  const size_t o_wdt = o_dbl + (size_t)MROWS * 256 * 2;

  u16* Abuf = (u16*)(ws + o_A);
  u16* Bbuf = (u16*)(ws + o_B);
  u16* Cbuf = (u16*)(ws + o_C);
  u16* Ebuf = (u16*)(ws + o_E);
  u16* Fbuf = (u16*)(ws + o_F);
  u16* dbl  = (u16*)(ws + o_dbl);
  u16* wdt  = (u16*)(ws + o_wdt);
  float* Pb = (float*)(ws + o_B);
  float* Sb = Pb + (size_t)2097152;
  float* Hb = Sb + (size_t)2097152;
  float* g3part = (float*)(ws + o_B);

  if (five) {
    // ----- Path A: fused G1 via compile-time MODE 8 -----
    u16* wio = Ebuf;              // 4096 x 1024 (8 MiB)
    u16* wii = Ebuf + 4194304;    // 4096 x 2048 (16 MiB)
    u16* wxp = Ebuf + 12582912;   // 256 x 2048  (1 MiB)
    u16* woi = Bbuf;              // post-scan reuse of B
    u16* woo = Bbuf + 4194304;

    cvt_bf16<<<(MROWS * 1024 / 4 + 255) / 256, 256, 0, stream>>>(x, Bbuf, MROWS * 1024 / 4);
    {
      TBatch tb1;
      tb1.n = 5;
      tb1.d[0] = { W_in_o, wio, 1024, 4096, 0, 4096, 4096 };
      tb1.d[1] = { W_in_i, wii, 2048, 4096, 0, 2048, 2048 };
      tb1.d[2] = { W_in_i, wii + (size_t)2048 * 2048, 2048, 4096, 2048, 2048, 2048 };
      tb1.d[3] = { W_xp, wxp, 2048, 160, 0, 160, 256 };
      tb1.d[4] = { W_dt, wdt, 128, 2048, 0, 2048, 2048 };
      transpose_batch<<<dim3(64, 128, 5), dim3(32, 8), 0, stream>>>(tb1);
    }
    // G1 fused (MODE 8): xp|zp = x_bf @ wio + b_in_o (split xp->A, zp->F)
    gemm256<8><<<dim3(32, 16), 512, 0, stream>>>(Bbuf, 1024, wio, Abuf, Fbuf, 2048, 1024, b_in_o, nullptr, 0);
    // G2 (MODE 6, r18-identical): xm|zm = xp @ wii
    gemm256<6><<<dim3(32, 16), 512, 0, stream>>>(Abuf, 2048, wii, Bbuf, Cbuf, 2048, 2048, nullptr, nullptr, 0);
    conv_silu<<<(MROWS * DI / 8) / 256, 256, 0, stream>>>(Bbuf, conv_w, conv_b, Abuf);
    gemm_bt<7><<<dim3(64, 2, 2), 256, 0, stream>>>(Abuf, 2048, wxp, 2048, g3part, 256, 1024, nullptr, nullptr, 0);
    combine_dbl<<<(MROWS * 256 / 4 + 255) / 256, 256, 0, stream>>>(g3part, dbl, MROWS * 256 / 4);
    gemm_bt<3><<<dim3(64, 16), 256, 0, stream>>>(dbl, 256, wdt, 128, Ebuf, 2048, 128, b_dt, nullptr, 0);
    scan_phaseA<<<BB * NCH * 8, 256, 0, stream>>>(Ebuf, dbl, Abuf, Pb, Sb);
    scan_phaseB<<<512, 256, 0, stream>>>(Pb, Sb, Hb);
    scan_phaseC<<<BB * NCH * 8, 256, 0, stream>>>(Ebuf, dbl, Abuf, Cbuf, D_skip, Hb);
    {
      TBatch tb2;
      tb2.n = 2;
      tb2.d[0] = { W_out_i, woi, 2048, 2048, 0, 2048, 2048 };
      tb2.d[1] = { W_out_o, woo, 2048, 1024, 0, 1024, 1024 };
      tb2.d[2] = { nullptr, nullptr, 0, 0, 0, 0, 0 };
      tb2.d[3] = { nullptr, nullptr, 0, 0, 0, 0, 0 };
      tb2.d[4] = { nullptr, nullptr, 0, 0, 0, 0, 0 };
      transpose_batch<<<dim3(64, 64, 2), dim3(32, 8), 0, stream>>>(tb2);
    }
    // G5: o2 = (yg @ woi) * sigmoid(zp in F)
    gemm256<4><<<dim3(32, 8), 512, 0, stream>>>(Cbuf, 2048, woi, Abuf, nullptr, 2048, 2048, nullptr, Fbuf, 2048);
    gemm_bt<5><<<dim3(64, 8), 256, 0, stream>>>(Abuf, 2048, woo, 2048, out, 1024, 2048, b_out_o, nullptr, 0);
  } else {
    // ----- Path B: exact round-18 sequence -----
    u16* wio_a = Ebuf;
    u16* wii   = Ebuf + 2097152;
    u16* wxp   = Ebuf + 10485760;
    u16* wio_b = Bbuf;
    u16* woi   = Bbuf + 2097152;
    u16* woo   = Bbuf + 6291456;
    u16* xbf2  = Bbuf + 8388608;

    cvt_bf16<<<(MROWS * 1024 / 4 + 255) / 256, 256, 0, stream>>>(x, Bbuf, MROWS * 1024 / 4);
    {
      TBatch tb1;
      tb1.n = 5;
      tb1.d[0] = { W_in_o, wio_a, 1024, 4096, 0, 2048, 2048 };
      tb1.d[1] = { W_in_i, wii, 2048, 4096, 0, 2048, 2048 };
      tb1.d[2] = { W_in_i, wii + (size_t)2048 * 2048, 2048, 4096, 2048, 2048, 2048 };
      tb1.d[3] = { W_xp, wxp, 2048, 160, 0, 160, 256 };
      tb1.d[4] = { W_dt, wdt, 128, 2048, 0, 2048, 2048 };
      transpose_batch<<<dim3(64, 64, 5), dim3(32, 8), 0, stream>>>(tb1);
    }
    gemm256<1><<<dim3(32, 8), 512, 0, stream>>>(Bbuf, 1024, wio_a, Abuf, nullptr, 2048, 1024, b_in_o, nullptr, 0);
    gemm256<6><<<dim3(32, 16), 512, 0, stream>>>(Abuf, 2048, wii, Bbuf, Cbuf, 2048, 2048, nullptr, nullptr, 0);
    conv_silu<<<(MROWS * DI / 8) / 256, 256, 0, stream>>>(Bbuf, conv_w, conv_b, Abuf);
    gemm_bt<7><<<dim3(64, 2, 2), 256, 0, stream>>>(Abuf, 2048, wxp, 2048, g3part, 256, 1024, nullptr, nullptr, 0);
    combine_dbl<<<(MROWS * 256 / 4 + 255) / 256, 256, 0, stream>>>(g3part, dbl, MROWS * 256 / 4);
    gemm_bt<3><<<dim3(64, 16), 256, 0, stream>>>(dbl, 256, wdt, 128, Ebuf, 2048, 128, b_dt, nullptr, 0);
    scan_phaseA<<<BB * NCH * 8, 256, 0, stream>>>(Ebuf, dbl, Abuf, Pb, Sb);
    scan_phaseB<<<512, 256, 0, stream>>>(Pb, Sb, Hb);
    scan_phaseC<<<BB * NCH * 8, 256, 0, stream>>>(Ebuf, dbl, Abuf, Cbuf, D_skip, Hb);
    cvt_bf16<<<(MROWS * 1024 / 4 + 255) / 256, 256, 0, stream>>>(x, xbf2, MROWS * 1024 / 4);
    {
      TBatch tb2;
      tb2.n = 3;
      tb2.d[0] = { W_in_o, wio_b, 1024, 4096, 2048, 2048, 2048 };
      tb2.d[1] = { W_out_i, woi, 2048, 2048, 0, 2048, 2048 };
      tb2.d[2] = { W_out_o, woo, 2048, 1024, 0, 1024, 1024 };
      tb2.d[3] = { nullptr, nullptr, 0, 0, 0, 0, 0 };
      tb2.d[4] = { nullptr, nullptr, 0, 0, 0, 0, 0 };
      transpose_batch<<<dim3(64, 64, 3), dim3(32, 8), 0, stream>>>(tb2);
    }
    gemm256<1><<<dim3(32, 8), 512, 0, stream>>>(xbf2, 1024, wio_b, Ebuf, nullptr, 2048, 1024, b_in_o + 2048, nullptr, 0);
    gemm256<4><<<dim3(32, 8), 512, 0, stream>>>(Cbuf, 2048, woi, Abuf, nullptr, 2048, 2048, nullptr, Ebuf, 2048);
    gemm_bt<5><<<dim3(64, 8), 256, 0, stream>>>(Abuf, 2048, woo, 2048, out, 1024, 2048, b_out_o, nullptr, 0);
  }
}

// Round 22
// 625.905 us; speedup vs baseline: 1.0527x; 1.0138x over previous
//
#include <hip/hip_runtime.h>
#include <stdint.h>
#include <math.h>

// ---------------------------------------------------------------------------
// SimpleMamba2Like on MI355X — Round 22: REVERT to round 18 verbatim (the
// session's measured optimum, 625.0 us). Rounds 19-21 proved the G1-fusion
// family net-negative (bias_add traffic / runtime-branch codegen / fused
// launch overhead); all other levers were null or locked in earlier.
// Pipeline: cvt -> T(batch1) -> G1a[256sq] -> G2 fused xm|zm [256sq] ->
// conv(vec8) -> G3 split-K + combine(f32 B/C pack) -> G4 -> 3-phase
// chunk-parallel serial-n scan -> cvt -> T(batch2) -> G1b -> G5 -> G6.
// ---------------------------------------------------------------------------

typedef unsigned short u16;
typedef __bf16 bf16x8 __attribute__((ext_vector_type(8)));
typedef u16 u16x8 __attribute__((ext_vector_type(8)));
typedef u16 u16x4 __attribute__((ext_vector_type(4)));
typedef float f32x4 __attribute__((ext_vector_type(4)));

static constexpr int BB = 4, SS = 2048, DI = 2048, DST = 16, DTR = 128;
static constexpr int MROWS = BB * SS; // 8192
static constexpr int NCH = 16, CL = 128;

__device__ __forceinline__ float bf2f(u16 x) {
  union { unsigned u; float f; } v; v.u = ((unsigned)x) << 16; return v.f;
}
__device__ __forceinline__ u16 f2bf(float f) {
  union { float f; unsigned u; } v; v.f = f;
  unsigned r = (v.u + 0x7FFFu + ((v.u >> 16) & 1u)) >> 16; // RNE
  return (u16)r;
}
__device__ __forceinline__ float sigmoidf_(float x) { return 1.f / (1.f + __expf(-x)); }
__device__ __forceinline__ float softplusf_(float x) {
  return fmaxf(x, 0.f) + log1pf(__expf(-fabsf(x)));
}
__device__ __forceinline__ void async16(u16* lds, const u16* g) {
  __builtin_amdgcn_global_load_lds(
      (__attribute__((address_space(1))) void*)g,
      (__attribute__((address_space(3))) void*)lds, 16, 0, 0);
}

// ---------------------------------------------------------------------------
__global__ __launch_bounds__(256) void cvt_bf16(const float* __restrict__ in,
                                                u16* __restrict__ out, int n4) {
  const int i = blockIdx.x * 256 + threadIdx.x;
  if (i >= n4) return;
  f32x4 v = *(const f32x4*)(in + (size_t)i * 4);
  u16x4 o = { f2bf(v[0]), f2bf(v[1]), f2bf(v[2]), f2bf(v[3]) };
  *(u16x4*)(out + (size_t)i * 4) = o;
}

// ---------------------------------------------------------------------------
// Combine G3 split-K partials. cols<128 -> bf16 dt; cols 128..159 -> ALSO
// raw f32 packed at dbl row-tail bytes [320,448).
// ---------------------------------------------------------------------------
__global__ __launch_bounds__(256) void combine_dbl(const float* __restrict__ P,
                                                   u16* __restrict__ dbl, int n4) {
  const int i = blockIdx.x * 256 + threadIdx.x;
  if (i >= n4) return;
  const float* P1 = P + (size_t)MROWS * 256;
  f32x4 a = *(const f32x4*)(P + (size_t)i * 4);
  f32x4 b = *(const f32x4*)(P1 + (size_t)i * 4);
  f32x4 s = { a[0] + b[0], a[1] + b[1], a[2] + b[2], a[3] + b[3] };
  const int col = (i * 4) & 255;
  const int row = (i * 4) >> 8;
  if (col < 128) {
    u16x4 o = { f2bf(s[0]), f2bf(s[1]), f2bf(s[2]), f2bf(s[3]) };
    *(u16x4*)&dbl[(size_t)row * 256 + col] = o;
  } else if (col < 160) {
    // packed f32 B/C: byte offset row*512 + 320 + (col-128)*4 (16B aligned)
    float* fp = (float*)dbl + (size_t)row * 128 + 80 + (col - 128);
    *(f32x4*)fp = s;
  }
}

// ---------------------------------------------------------------------------
// Batched transpose. blockIdx.z selects a descriptor.
// ---------------------------------------------------------------------------
struct TDesc {
  const float* in;
  u16* out;
  int K, N_full, n_off, N_sub, Npad;
};
struct TBatch { TDesc d[5]; int n; };

__global__ void transpose_batch(TBatch batch) {
  if ((int)blockIdx.z >= batch.n) return;
  const TDesc dd = batch.d[blockIdx.z];
  const int k0 = blockIdx.x * 32, n0 = blockIdx.y * 32;
  if (k0 >= dd.K || n0 >= dd.Npad) return; // block-uniform exit (pre-LDS)
  __shared__ u16 tile[32][33];
  const int tx = threadIdx.x, ty = threadIdx.y; // 32 x 8
#pragma unroll
  for (int i = 0; i < 4; ++i) {
    int k = k0 + ty + i * 8, nn = n0 + tx;
    tile[ty + i * 8][tx] =
        (k < dd.K && nn < dd.N_sub)
            ? f2bf(dd.in[(size_t)k * dd.N_full + dd.n_off + nn]) : (u16)0;
  }
  __syncthreads();
#pragma unroll
  for (int i = 0; i < 4; ++i) {
    int nn = n0 + ty + i * 8, k = k0 + tx;
    if (nn < dd.Npad && k < dd.K) dd.out[(size_t)nn * dd.K + k] = tile[tx][ty + i * 8];
  }
}

// ---------------------------------------------------------------------------
// 256x256-tile GEMM (r14): T2-swizzled LDS, wave layout 2M x 4N, one counted
// vmcnt(2) per K-tile (q3), one barrier per phase.
// MODE 1: +bias bf16  MODE 4: *sigmoid(gate) bf16  MODE 6: split store
// ---------------------------------------------------------------------------
template <int MODE>
__global__ __launch_bounds__(512, 1) void gemm256(
    const u16* __restrict__ A, int lda, const u16* __restrict__ BT,
    void* __restrict__ C0v, void* __restrict__ C1v, int ldc, int K,
    const float* __restrict__ bias, const u16* __restrict__ gate, int ldg) {
  __shared__ u16 lds[73728]; // 144 KiB
  const int m0 = blockIdx.x * 256, n0 = blockIdx.y * 256;
  const int t = threadIdx.x, w = t >> 6, l = t & 63;
  const int lr = l & 15, lg = l >> 4;
  const int mhalf = w >> 2, nquad = w & 3;
  const int bslot_h = nquad >> 1, brow0 = (nquad & 1) * 64;
  const int NT = K >> 6;
  const int srow = t >> 3;
  const int sc8 = (t & 7) ^ (srow & 7); // T2: inverse-swizzled source col
  const int rsw = (lr & 7) << 3;        // T2: element-XOR for ds_read

#define A1SLOT(tile) ((((tile) & 1)) * 8192)
#define A0SLOT(s3) (16384 + (s3) * 8192)
#define BSLOT(tile, h) (40960 + (((tile) & 1) * 2 + (h)) * 8192)
#define STAGE_A0(tile, s3)                                                      \
  {                                                                             \
    const u16* _g = A + (size_t)(m0 + srow) * lda + (tile) * 64 + sc8 * 8;      \
    async16(&lds[A0SLOT(s3) + w * 512], _g);                                    \
    async16(&lds[A0SLOT(s3) + 4096 + w * 512], _g + (size_t)64 * lda);          \
  }
#define STAGE_A1(tile)                                                          \
  {                                                                             \
    const u16* _g = A + (size_t)(m0 + 128 + srow) * lda + (tile) * 64 + sc8 * 8;\
    async16(&lds[A1SLOT(tile) + w * 512], _g);                                  \
    async16(&lds[A1SLOT(tile) + 4096 + w * 512], _g + (size_t)64 * lda);        \
  }
#define STAGE_B(tile, h)                                                        \
  {                                                                             \
    const u16* _g = BT + (size_t)(n0 + (h) * 128 + srow) * K +                  \
                    (tile) * 64 + sc8 * 8;                                      \
    async16(&lds[BSLOT(tile, h) + w * 512], _g);                                \
    async16(&lds[BSLOT(tile, h) + 4096 + w * 512], _g + (size_t)64 * K);        \
  }

  f32x4 acc[8][4] = {};
  u16x8 bfr[4][2];

  STAGE_A0(0, 0); STAGE_A1(0); STAGE_B(0, 0); STAGE_B(0, 1); STAGE_A0(1, 1);
  asm volatile("s_waitcnt vmcnt(2)" ::: "memory");
  __builtin_amdgcn_s_barrier();
  asm volatile("" ::: "memory");
  int cur0 = 0;

  for (int T = 0; T < NT; ++T) {
    const int abase = mhalf ? A1SLOT(T) : A0SLOT(cur0);
    const int bbase = BSLOT(T, bslot_h);
#pragma unroll
    for (int q = 0; q < 4; ++q) {
      if (q == 0) {
#pragma unroll
        for (int fn = 0; fn < 4; ++fn)
#pragma unroll
          for (int ks = 0; ks < 2; ++ks)
            bfr[fn][ks] = *(const u16x8*)&lds[
                bbase + (brow0 + fn * 16 + lr) * 64 + ((ks * 32 + lg * 8) ^ rsw)];
      }
      u16x8 af[2][2];
#pragma unroll
      for (int j = 0; j < 2; ++j)
#pragma unroll
        for (int ks = 0; ks < 2; ++ks)
          af[j][ks] = *(const u16x8*)&lds[
              abase + ((q * 2 + j) * 16 + lr) * 64 + ((ks * 32 + lg * 8) ^ rsw)];
      if (q == 0) { if (T + 1 < NT) { STAGE_B(T + 1, 0); STAGE_A1(T + 1); } }
      else if (q == 1) { if (T + 1 < NT) { STAGE_B(T + 1, 1); } }
      else if (q == 2) {
        if (T + 2 < NT) {
          int s3 = cur0 + 2; if (s3 >= 3) s3 -= 3;
          STAGE_A0(T + 2, s3);
        }
      }
      if (q == 3) asm volatile("s_waitcnt vmcnt(2)" ::: "memory");
      __builtin_amdgcn_s_barrier();
      asm volatile("" ::: "memory");
      __builtin_amdgcn_s_setprio(1);
#pragma unroll
      for (int j = 0; j < 2; ++j)
#pragma unroll
        for (int fn = 0; fn < 4; ++fn)
#pragma unroll
          for (int ks = 0; ks < 2; ++ks)
            acc[q * 2 + j][fn] = __builtin_amdgcn_mfma_f32_16x16x32_bf16(
                __builtin_bit_cast(bf16x8, af[j][ks]),
                __builtin_bit_cast(bf16x8, bfr[fn][ks]), acc[q * 2 + j][fn],
                0, 0, 0);
      __builtin_amdgcn_s_setprio(0);
    }
    ++cur0; if (cur0 == 3) cur0 = 0;
  }

#pragma unroll
  for (int fm = 0; fm < 8; ++fm) {
#pragma unroll
    for (int fn = 0; fn < 4; ++fn) {
#pragma unroll
      for (int r = 0; r < 4; ++r) {
        const int row = m0 + mhalf * 128 + fm * 16 + lg * 4 + r;
        const int col = n0 + nquad * 64 + fn * 16 + lr;
        float v = acc[fm][fn][r];
        if constexpr (MODE == 1) v += bias[col];
        if constexpr (MODE == 4) v *= sigmoidf_(bf2f(gate[(size_t)row * ldg + col]));
        if constexpr (MODE == 6) {
          if (col < 2048) ((u16*)C0v)[(size_t)row * ldc + col] = f2bf(v);
          else            ((u16*)C1v)[(size_t)row * ldc + col - 2048] = f2bf(v);
        } else {
          ((u16*)C0v)[(size_t)row * ldc + col] = f2bf(v);
        }
      }
    }
  }
#undef A1SLOT
#undef A0SLOT
#undef BSLOT
#undef STAGE_A0
#undef STAGE_A1
#undef STAGE_B
}

// ---------------------------------------------------------------------------
// 128x128 GEMM. ldb = BT row stride. MODE 0: bf16; 3: +bias, softplus;
// 5: +bias, f32 store; 7: f32 partial store (split-K via blockIdx.z).
// ---------------------------------------------------------------------------
template <int MODE>
__global__ __launch_bounds__(256) void gemm_bt(
    const u16* __restrict__ A, int lda, const u16* __restrict__ BT, int ldb,
    void* __restrict__ Cv, int ldc, int K,
    const float* __restrict__ bias, const u16* __restrict__ gate, int ldg) {
  __shared__ u16 Asm[128 * 32];
  __shared__ u16 Bsm[128 * 32];
  const int m0 = blockIdx.x * 128, n0 = blockIdx.y * 128;
  if constexpr (MODE == 7) {
    const int kz = blockIdx.z;
    A += (size_t)kz * 1024;
    BT += (size_t)kz * 1024;
  }
  const int t = threadIdx.x;
  const int wave = t >> 6, lane = t & 63;
  const int wm = (wave >> 1) * 64, wn = (wave & 1) * 64;
  const int lr = lane & 15, lg = lane >> 4;
  const int sr = t >> 2, sc = (t & 3) * 8;
  const int wbase = wave * 512;
  const u16* Ap0 = A + (size_t)(m0 + sr) * lda + sc;
  const u16* Ap1 = A + (size_t)(m0 + 64 + sr) * lda + sc;
  const u16* Bp0 = BT + (size_t)(n0 + sr) * ldb + sc;
  const u16* Bp1 = BT + (size_t)(n0 + 64 + sr) * ldb + sc;

  f32x4 acc[4][4] = {};
  const int nk = K >> 5;
  for (int kt = 0; kt < nk; ++kt) {
    const int ko = kt * 32;
    __syncthreads();
    async16(&Asm[wbase], Ap0 + ko);
    async16(&Asm[2048 + wbase], Ap1 + ko);
    async16(&Bsm[wbase], Bp0 + ko);
    async16(&Bsm[2048 + wbase], Bp1 + ko);
    __syncthreads();
    u16x8 afu[4], bfu[4];
#pragma unroll
    for (int i = 0; i < 4; ++i)
      afu[i] = *(const u16x8*)&Asm[(wm + i * 16 + lr) * 32 + lg * 8];
#pragma unroll
    for (int j = 0; j < 4; ++j)
      bfu[j] = *(const u16x8*)&Bsm[(wn + j * 16 + lr) * 32 + lg * 8];
#pragma unroll
    for (int i = 0; i < 4; ++i)
#pragma unroll
      for (int j = 0; j < 4; ++j)
        acc[i][j] = __builtin_amdgcn_mfma_f32_16x16x32_bf16(
            __builtin_bit_cast(bf16x8, afu[i]), __builtin_bit_cast(bf16x8, bfu[j]),
            acc[i][j], 0, 0, 0);
  }
#pragma unroll
  for (int i = 0; i < 4; ++i) {
#pragma unroll
    for (int j = 0; j < 4; ++j) {
#pragma unroll
      for (int r = 0; r < 4; ++r) {
        const int row = m0 + wm + i * 16 + lg * 4 + r;
        const int col = n0 + wn + j * 16 + lr;
        float v = acc[i][j][r];
        if constexpr (MODE == 3 || MODE == 5) v += bias[col];
        if constexpr (MODE == 3) v = softplusf_(v);
        if constexpr (MODE == 5)
          ((float*)Cv)[(size_t)row * ldc + col] = v;
        else if constexpr (MODE == 7)
          ((float*)Cv)[(size_t)blockIdx.z * MROWS * 256 + (size_t)row * ldc + col] = v;
        else
          ((u16*)Cv)[(size_t)row * ldc + col] = f2bf(v);
      }
    }
  }
}

// ---------------------------------------------------------------------------
// Causal depthwise conv (k=4) + SiLU, vectorized: 1 thread = 8 d's.
// ---------------------------------------------------------------------------
__global__ __launch_bounds__(256) void conv_silu(
    const u16* __restrict__ xm, const float* __restrict__ cw,
    const float* __restrict__ cb, u16* __restrict__ xc) {
  const int tid = blockIdx.x * 256 + threadIdx.x; // over MROWS*DI/8
  const size_t base = (size_t)tid * 8;
  const int d8 = (int)(base & (DI - 1));
  const int row = (int)(base >> 11);
  const int s = row & (SS - 1);
  u16x8 xv[4];
#pragma unroll
  for (int j = 0; j < 4; ++j) {
    xv[j] = ((s - 3 + j) >= 0) ? *(const u16x8*)&xm[(size_t)(row - 3 + j) * DI + d8]
                               : (u16x8){0, 0, 0, 0, 0, 0, 0, 0};
  }
  u16x8 o;
#pragma unroll
  for (int dd = 0; dd < 8; ++dd) {
    f32x4 wv = *(const f32x4*)(cw + (size_t)(d8 + dd) * 4);
    float acc = cb[d8 + dd];
#pragma unroll
    for (int j = 0; j < 4; ++j)
      acc += bf2f(xv[j][dd]) * wv[j];
    float r = acc * sigmoidf_(acc);
    o[dd] = f2bf(r);
  }
  *(u16x8*)&xc[base] = o;
}

// ---------------------------------------------------------------------------
// Serial-n chunk-parallel scan; B/C read as raw f32 from the dbl row tail
// ((float*)dbl + row*128 + 80): no bf16 unpack in the issue-bound loop.
// ---------------------------------------------------------------------------
__global__ __launch_bounds__(256) void scan_phaseA(
    const u16* __restrict__ delta, const u16* __restrict__ dbl,
    const u16* __restrict__ u_in,
    float* __restrict__ Pb, float* __restrict__ Sb) {
  const int t = threadIdx.x;
  const int bid = blockIdx.x;
  const int dblk = bid & 7;
  const int c = (bid >> 3) & 15;
  const int b = bid >> 7;
  const int d = dblk * 256 + t;
  const int s0 = c * CL;
  const u16* dp = delta + (size_t)(b * SS + s0) * DI + d;
  const u16* up = u_in + (size_t)(b * SS + s0) * DI + d;
  const float* bcf = (const float*)dbl + (size_t)(b * SS + s0) * 128 + 80;
  float h[16];
#pragma unroll
  for (int n = 0; n < 16; ++n) h[n] = 0.f;
  float L = 0.f;
  float dt_c = bf2f(dp[0]);
  float u_c = bf2f(up[0]);
  for (int s = 0; s < CL; ++s) {
    dp += DI; up += DI;
    float dt_n = bf2f(dp[0]); // 1-step prefetch
    float u_n = bf2f(up[0]);
    f32x4 wB[4];
#pragma unroll
    for (int i = 0; i < 4; ++i) wB[i] = *(const f32x4*)(bcf + 4 * i);
    bcf += 128;
    float e1 = __expf(-dt_c);
    float dtu = dt_c * u_c;
    L += dt_c;
    float e = 1.f;
#pragma unroll
    for (int i = 0; i < 4; ++i) {
#pragma unroll
      for (int k = 0; k < 4; ++k) {
        e *= e1;
        h[4 * i + k] = fmaf(e, h[4 * i + k], dtu * wB[i][k]);
      }
    }
    dt_c = dt_n; u_c = u_n;
  }
  const float E = __expf(-L);
  const size_t base = (((size_t)(b * DI + d)) * 16) * NCH + c;
  float P = 1.f;
#pragma unroll
  for (int n = 0; n < 16; ++n) {
    P *= E;
    Pb[base + (size_t)n * NCH] = P;
    Sb[base + (size_t)n * NCH] = h[n];
  }
}

__global__ __launch_bounds__(256) void scan_phaseB(
    const float* __restrict__ Pb, const float* __restrict__ Sb,
    float* __restrict__ Hb) {
  const size_t tid = (size_t)blockIdx.x * 256 + threadIdx.x;
  const size_t base = tid * NCH;
  float h = 0.f;
#pragma unroll
  for (int cc = 0; cc < NCH; ++cc) {
    Hb[base + cc] = h;
    h = Sb[base + cc] + Pb[base + cc] * h;
  }
}

__global__ __launch_bounds__(256) void scan_phaseC(
    const u16* __restrict__ delta, const u16* __restrict__ dbl,
    const u16* __restrict__ u_in, u16* __restrict__ zy,
    const float* __restrict__ D_skip, const float* __restrict__ Hb) {
  const int t = threadIdx.x;
  const int bid = blockIdx.x;
  const int dblk = bid & 7;
  const int c = (bid >> 3) & 15;
  const int b = bid >> 7;
  const int d = dblk * 256 + t;
  const float Dsk = D_skip[d];
  const size_t hbase = (((size_t)(b * DI + d)) * 16) * NCH + c;
  float h[16];
#pragma unroll
  for (int n = 0; n < 16; ++n) h[n] = Hb[hbase + (size_t)n * NCH];
  const int s0 = c * CL;
  const u16* dp = delta + (size_t)(b * SS + s0) * DI + d;
  const u16* up = u_in + (size_t)(b * SS + s0) * DI + d;
  u16* zp = zy + (size_t)(b * SS + s0) * DI + d;
  const float* bcf = (const float*)dbl + (size_t)(b * SS + s0) * 128 + 80;
  float dt_c = bf2f(dp[0]);
  float u_c = bf2f(up[0]);
  float z_c = bf2f(zp[0]);
  for (int s = 0; s < CL; ++s) {
    dp += DI; up += DI;
    float dt_n = bf2f(dp[0]); // 1-step prefetch
    float u_n = bf2f(up[0]);
    float z_n = bf2f(zp[DI]);
    f32x4 wB[4], wC[4];
#pragma unroll
    for (int i = 0; i < 4; ++i) {
      wB[i] = *(const f32x4*)(bcf + 4 * i);
      wC[i] = *(const f32x4*)(bcf + 16 + 4 * i);
    }
    bcf += 128;
    float e1 = __expf(-dt_c);
    float dtu = dt_c * u_c;
    float e = 1.f, y = 0.f;
#pragma unroll
    for (int i = 0; i < 4; ++i) {
#pragma unroll
      for (int k = 0; k < 4; ++k) {
        e *= e1;
        h[4 * i + k] = fmaf(e, h[4 * i + k], dtu * wB[i][k]);
        y = fmaf(h[4 * i + k], wC[i][k], y);
      }
    }
    float yo = (y + Dsk * u_c) * (z_c * sigmoidf_(z_c));
    zp[0] = f2bf(yo);
    zp += DI;
    dt_c = dt_n; u_c = u_n; z_c = z_n;
  }
}

// ---------------------------------------------------------------------------
extern "C" void kernel_launch(void* const* d_in, const int* in_sizes, int n_in,
                              void* d_out, int out_size, void* d_ws, size_t ws_size,
                              hipStream_t stream) {
  const float* x       = (const float*)d_in[0];
  const float* W_in_o  = (const float*)d_in[1];
  const float* b_in_o  = (const float*)d_in[2];
  const float* W_out_o = (const float*)d_in[3];
  const float* b_out_o = (const float*)d_in[4];
  const float* W_in_i  = (const float*)d_in[5];
  const float* conv_w  = (const float*)d_in[6];
  const float* conv_b  = (const float*)d_in[7];
  const float* W_xp    = (const float*)d_in[8];
  const float* W_dt    = (const float*)d_in[9];
  const float* b_dt    = (const float*)d_in[10];
  const float* D_skip  = (const float*)d_in[12];
  const float* W_out_i = (const float*)d_in[13];
  float* out = (float*)d_out;
  char* ws = (char*)d_ws;

  const size_t SLOT = (size_t)MROWS * DI * 2; // 32 MiB
  const size_t o_A = 0;
  const size_t o_B = SLOT;
  const size_t o_C = 2 * SLOT;
  const size_t o_E = 3 * SLOT;
  const size_t o_dbl = 4 * SLOT;
  const size_t o_wdt = o_dbl + (size_t)MROWS * 256 * 2;
  const size_t need = o_wdt + (size_t)2048 * 128 * 2; // ~132.5 MiB
  if (need > ws_size) return;

  u16* Abuf = (u16*)(ws + o_A);
  u16* Bbuf = (u16*)(ws + o_B);
  u16* Cbuf = (u16*)(ws + o_C);
  u16* Ebuf = (u16*)(ws + o_E);
  u16* dbl  = (u16*)(ws + o_dbl);
  u16* wdt  = (u16*)(ws + o_wdt);
  float* Pb = (float*)(ws + o_B);
  float* Sb = Pb + (size_t)2097152;
  float* Hb = Sb + (size_t)2097152;
  float* g3part = (float*)(ws + o_B);
  u16* wio_a = Ebuf;
  u16* wii   = Ebuf + 2097152;
  u16* wxp   = Ebuf + 10485760;
  u16* wio_b = Bbuf;
  u16* woi   = Bbuf + 2097152;
  u16* woo   = Bbuf + 6291456;
  u16* xbf2  = Bbuf + 8388608;

  // x -> bf16 in B
  cvt_bf16<<<(MROWS * 1024 / 4 + 255) / 256, 256, 0, stream>>>(x, Bbuf, MROWS * 1024 / 4);
  // batch1: wio_a | wii_lo | wii_hi | wxp | wdt
  {
    TBatch tb1;
    tb1.n = 5;
    tb1.d[0] = { W_in_o, wio_a, 1024, 4096, 0, 2048, 2048 };
    tb1.d[1] = { W_in_i, wii, 2048, 4096, 0, 2048, 2048 };
    tb1.d[2] = { W_in_i, wii + (size_t)2048 * 2048, 2048, 4096, 2048, 2048, 2048 };
    tb1.d[3] = { W_xp, wxp, 2048, 160, 0, 160, 256 };
    tb1.d[4] = { W_dt, wdt, 128, 2048, 0, 2048, 2048 };
    transpose_batch<<<dim3(64, 64, 5), dim3(32, 8), 0, stream>>>(tb1);
  }
  // G1a: xp = x_bf @ wio_a + b_in_o[:2048]                  -> A   [256sq]
  gemm256<1><<<dim3(32, 8), 512, 0, stream>>>(Bbuf, 1024, wio_a, Abuf, nullptr, 2048, 1024, b_in_o, nullptr, 0);
  // G2: xm|zm = xp @ wii (N=4096 fused, split store)         -> B,C [256sq]
  gemm256<6><<<dim3(32, 16), 512, 0, stream>>>(Abuf, 2048, wii, Bbuf, Cbuf, 2048, 2048, nullptr, nullptr, 0);
  // conv: xc = silu(conv(xm))                                B -> A (vec x8)
  conv_silu<<<(MROWS * DI / 8) / 256, 256, 0, stream>>>(Bbuf, conv_w, conv_b, Abuf);
  // G3 split-K: partials = xc @ wxp (z = K-half)             -> B (f32)
  gemm_bt<7><<<dim3(64, 2, 2), 256, 0, stream>>>(Abuf, 2048, wxp, 2048, g3part, 256, 1024, nullptr, nullptr, 0);
  // combine partials -> dbl (bf16 dt + packed f32 B/C)
  combine_dbl<<<(MROWS * 256 / 4 + 255) / 256, 256, 0, stream>>>(g3part, dbl, MROWS * 256 / 4);
  // G4: delta = softplus(dbl[:, :128] @ wdt + b_dt)          -> E
  gemm_bt<3><<<dim3(64, 16), 256, 0, stream>>>(dbl, 256, wdt, 128, Ebuf, 2048, 128, b_dt, nullptr, 0);
  // chunk-parallel scan; yg in-place over zm (C)
  scan_phaseA<<<BB * NCH * 8, 256, 0, stream>>>(Ebuf, dbl, Abuf, Pb, Sb);
  scan_phaseB<<<512, 256, 0, stream>>>(Pb, Sb, Hb);
  scan_phaseC<<<BB * NCH * 8, 256, 0, stream>>>(Ebuf, dbl, Abuf, Cbuf, D_skip, Hb);
  // x -> bf16 again (into B tail; PSH dead)
  cvt_bf16<<<(MROWS * 1024 / 4 + 255) / 256, 256, 0, stream>>>(x, xbf2, MROWS * 1024 / 4);
  // batch2: wio_b | woi | woo
  {
    TBatch tb2;
    tb2.n = 3;
    tb2.d[0] = { W_in_o, wio_b, 1024, 4096, 2048, 2048, 2048 };
    tb2.d[1] = { W_out_i, woi, 2048, 2048, 0, 2048, 2048 };
    tb2.d[2] = { W_out_o, woo, 2048, 1024, 0, 1024, 1024 };
    tb2.d[3] = { nullptr, nullptr, 0, 0, 0, 0, 0 };
    tb2.d[4] = { nullptr, nullptr, 0, 0, 0, 0, 0 };
    transpose_batch<<<dim3(64, 64, 3), dim3(32, 8), 0, stream>>>(tb2);
  }
  // G1b: zp = x_bf2 @ wio_b + b_in_o[2048:]                  -> E   [256sq]
  gemm256<1><<<dim3(32, 8), 512, 0, stream>>>(xbf2, 1024, wio_b, Ebuf, nullptr, 2048, 1024, b_in_o + 2048, nullptr, 0);
  // G5: o2 = (yg @ woi) * sigmoid(zp)                        -> A   [256sq]
  gemm256<4><<<dim3(32, 8), 512, 0, stream>>>(Cbuf, 2048, woi, Abuf, nullptr, 2048, 2048, nullptr, Ebuf, 2048);
  // G6: out = o2 @ woo + b_out_o  (f32 store)
  gemm_bt<5><<<dim3(64, 8), 256, 0, stream>>>(Abuf, 2048, woo, 2048, out, 1024, 2048, b_out_o, nullptr, 0);
}